// Round 1
// baseline (5534.647 us; speedup 1.0000x reference)
//
#include <hip/hip_runtime.h>
#include <cstdint>
#include <cstddef>

// ---------------------------------------------------------------------------
// AdaptiveLSTMBlockWrapper: ACT ponder loop.
// B=4096, IN=1024, H=1024, T=12. All fp32 (round 1: correctness + measure S).
//
// Key structure:
//  - Z1 = inputs @ W_ih1[:, :1024]^T + b_ih1 + b_hh1 precomputed once; flag
//    column W_ih1[:,1024] added only at step 0.
//  - Per step (gated on device-side continue count):
//      A: gates1 = Z1 + h1 @ W_hh1^T  -> c1,h1,act   (fused epilogue)
//      B: gates2 = b2 + act @ W_ih2^T + h2 @ W_hh2^T -> c2,h2
//      C1: z = h2n . w_halt + b_halt -> halting state machine per row
//      C2: acc_out += coef * h2n  (rows with coef != 0)
//  - acc_rem == halt_accum identically -> ponder_cost from halt_accum.
//  - h1/h2 ping-pong in ws (read old buf, write new buf -> no races).
//  - Z1 (64 MB) lives in d_out's h1..c2 regions; finalize overwrites them
//    with the real outputs at the end.
// ---------------------------------------------------------------------------

#define BATCH 4096
#define HDIM  1024
#define TSTEPS 12

// ws layout (float offsets)
#define ACT_OFS   0u
#define H1A_OFS   4194304u
#define H1B_OFS   8388608u
#define H2A_OFS   12582912u
#define H2B_OFS   16777216u
#define C1_OFS    20971520u
#define C2_OFS    25165824u
#define HALT_OFS  29360128u
#define CONT_OFS  29364224u
#define COEF_OFS  29368320u
#define CTRL_OFS  29372416u   // uint32: counts[12], steps_done at [12]

// d_out layout (float offsets)
#define O_ACC   0u
#define O_H1    4194304u
#define O_C1    8388608u
#define O_H2    12582912u
#define O_C2    16777216u
#define O_PCOST 20971520u
#define O_PSTEP 20971521u

__device__ __forceinline__ float sigmoidf_(float x) { return 1.0f / (1.0f + expf(-x)); }

// ---------------------------------------------------------------------------
// Shared GEMM-BT tile accumulator.
// Output tile: 64 batch rows (m0..) x [4 gates x 64 h-cols (n0..)].
// Virtual column v in [0,256): gate g = v>>6, h-col = n0 + (v&63).
// Weight row for v: g*1024 + n0 + (v&63), row-major stride `wstride` floats.
// LDS stored K-major: As2[k][row] (stride 68), Ws2[k][v] (stride 260) so the
// inner loop reads float4s (2-way bank aliasing only == free).
// Thread layout: 256 threads; ty=tid>>4 (4 rows each), tx=tid&15 (4 cols each).
// acc[r][g*4+c] = row m0+ty*4+r, gate g, h-col n0+tx*4+c.
// ---------------------------------------------------------------------------
__device__ __forceinline__ void gemm_acc(
    const float* __restrict__ Ain,   // [*][1024] row-major
    const float* __restrict__ W,     // [4096][wstride]
    int wstride, int m0, int n0,
    float (&acc)[4][16], float* As2, float* Ws2)
{
    const int tid  = threadIdx.x;
    const int ty4  = ((tid >> 4) & 15) << 2;
    const int tx4  = (tid & 15) << 2;
    const int lrow = tid >> 2;        // 0..63
    const int kq   = (tid & 3) << 2;  // 0,4,8,12

    for (int k0 = 0; k0 < 1024; k0 += 16) {
        __syncthreads();
        {
            const float4 v = *(const float4*)(Ain + (size_t)(m0 + lrow) * 1024 + k0 + kq);
            As2[(kq + 0) * 68 + lrow] = v.x;
            As2[(kq + 1) * 68 + lrow] = v.y;
            As2[(kq + 2) * 68 + lrow] = v.z;
            As2[(kq + 3) * 68 + lrow] = v.w;
#pragma unroll
            for (int p = 0; p < 4; ++p) {
                const int vr = p * 64 + lrow;
                const int wrow = ((vr >> 6) << 10) + n0 + (vr & 63);
                const float4 wv = *(const float4*)(W + (size_t)wrow * wstride + k0 + kq);
                Ws2[(kq + 0) * 260 + vr] = wv.x;
                Ws2[(kq + 1) * 260 + vr] = wv.y;
                Ws2[(kq + 2) * 260 + vr] = wv.z;
                Ws2[(kq + 3) * 260 + vr] = wv.w;
            }
        }
        __syncthreads();
#pragma unroll
        for (int k = 0; k < 16; ++k) {
            const float4 av = *(const float4*)&As2[k * 68 + ty4];
            const float a[4] = {av.x, av.y, av.z, av.w};
#pragma unroll
            for (int g = 0; g < 4; ++g) {
                const float4 wv = *(const float4*)&Ws2[k * 260 + g * 64 + tx4];
                const float w[4] = {wv.x, wv.y, wv.z, wv.w};
#pragma unroll
                for (int r = 0; r < 4; ++r) {
                    acc[r][g * 4 + 0] = fmaf(a[r], w[0], acc[r][g * 4 + 0]);
                    acc[r][g * 4 + 1] = fmaf(a[r], w[1], acc[r][g * 4 + 1]);
                    acc[r][g * 4 + 2] = fmaf(a[r], w[2], acc[r][g * 4 + 2]);
                    acc[r][g * 4 + 3] = fmaf(a[r], w[3], acc[r][g * 4 + 3]);
                }
            }
        }
    }
}

// Z1 = inputs @ W_ih1[:, :1024]^T + b_ih1 + b_hh1    (W_ih1 stride 1025)
__global__ __launch_bounds__(256) void k_z1(
    const float* __restrict__ x, const float* __restrict__ Wih1,
    const float* __restrict__ bih1, const float* __restrict__ bhh1,
    float* __restrict__ Z1)
{
    __shared__ float As2[16 * 68];
    __shared__ float Ws2[16 * 260];
    float acc[4][16];
#pragma unroll
    for (int r = 0; r < 4; ++r)
#pragma unroll
        for (int q = 0; q < 16; ++q) acc[r][q] = 0.0f;
    const int m0 = blockIdx.x * 64, n0 = blockIdx.y * 64;
    gemm_acc(x, Wih1, 1025, m0, n0, acc, As2, Ws2);
    const int tid = threadIdx.x, ty4 = ((tid >> 4) & 15) << 2, tx4 = (tid & 15) << 2;
#pragma unroll
    for (int r = 0; r < 4; ++r) {
        const int m = m0 + ty4 + r;
#pragma unroll
        for (int g = 0; g < 4; ++g)
#pragma unroll
            for (int c = 0; c < 4; ++c) {
                const int R = g * 1024 + n0 + tx4 + c;
                Z1[(size_t)m * 4096 + R] = acc[r][g * 4 + c] + bih1[R] + bhh1[R];
            }
    }
}

// Layer-1 cell: gates = Z1 (+flag col at step 0) + h1 @ W_hh1^T
__global__ __launch_bounds__(256) void k_stepA(
    const float* __restrict__ Z1, const float* __restrict__ Whh1,
    const float* __restrict__ Wih1, const float* __restrict__ h_in,
    float* __restrict__ c_st, float* __restrict__ h_out, float* __restrict__ act,
    const unsigned* __restrict__ cnt_prev, int step)
{
    if (step > 0 && cnt_prev[0] == 0u) return;
    __shared__ float As2[16 * 68];
    __shared__ float Ws2[16 * 260];
    float acc[4][16];
#pragma unroll
    for (int r = 0; r < 4; ++r)
#pragma unroll
        for (int q = 0; q < 16; ++q) acc[r][q] = 0.0f;
    const int m0 = blockIdx.x * 64, n0 = blockIdx.y * 64;
    gemm_acc(h_in, Whh1, 1024, m0, n0, acc, As2, Ws2);
    const int tid = threadIdx.x, ty4 = ((tid >> 4) & 15) << 2, tx4 = (tid & 15) << 2;
#pragma unroll
    for (int r = 0; r < 4; ++r) {
        const int m = m0 + ty4 + r;
#pragma unroll
        for (int c = 0; c < 4; ++c) {
            const int hc = n0 + tx4 + c;
            float p[4];
#pragma unroll
            for (int g = 0; g < 4; ++g) {
                p[g] = acc[r][g * 4 + c] + Z1[(size_t)m * 4096 + g * 1024 + hc];
                if (step == 0) p[g] += Wih1[(size_t)(g * 1024 + hc) * 1025 + 1024];
            }
            const float ig = sigmoidf_(p[0]);
            const float fg = sigmoidf_(p[1]);
            const float gg = tanhf(p[2]);
            const float og = sigmoidf_(p[3]);
            const int idx = m * 1024 + hc;
            const float cn = fg * c_st[idx] + ig * gg;
            const float hn = og * tanhf(cn);
            c_st[idx] = cn;
            h_out[idx] = hn;
            act[idx] = fmaxf(hn, 0.0f);
        }
    }
}

// Layer-2 cell: gates = b_ih2 + b_hh2 + act @ W_ih2^T + h2 @ W_hh2^T
__global__ __launch_bounds__(256) void k_stepB(
    const float* __restrict__ act, const float* __restrict__ Wih2,
    const float* __restrict__ Whh2, const float* __restrict__ bih2,
    const float* __restrict__ bhh2, const float* __restrict__ h_in,
    float* __restrict__ c_st, float* __restrict__ h_out,
    const unsigned* __restrict__ cnt_prev, int step)
{
    if (step > 0 && cnt_prev[0] == 0u) return;
    __shared__ float As2[16 * 68];
    __shared__ float Ws2[16 * 260];
    float acc[4][16];
#pragma unroll
    for (int r = 0; r < 4; ++r)
#pragma unroll
        for (int q = 0; q < 16; ++q) acc[r][q] = 0.0f;
    const int m0 = blockIdx.x * 64, n0 = blockIdx.y * 64;
    gemm_acc(act, Wih2, 1024, m0, n0, acc, As2, Ws2);
    gemm_acc(h_in, Whh2, 1024, m0, n0, acc, As2, Ws2);
    const int tid = threadIdx.x, ty4 = ((tid >> 4) & 15) << 2, tx4 = (tid & 15) << 2;
#pragma unroll
    for (int r = 0; r < 4; ++r) {
        const int m = m0 + ty4 + r;
#pragma unroll
        for (int c = 0; c < 4; ++c) {
            const int hc = n0 + tx4 + c;
            float p[4];
#pragma unroll
            for (int g = 0; g < 4; ++g) {
                const int R = g * 1024 + hc;
                p[g] = acc[r][g * 4 + c] + bih2[R] + bhh2[R];
            }
            const float ig = sigmoidf_(p[0]);
            const float fg = sigmoidf_(p[1]);
            const float gg = tanhf(p[2]);
            const float og = sigmoidf_(p[3]);
            const int idx = m * 1024 + hc;
            const float cn = fg * c_st[idx] + ig * gg;
            const float hn = og * tanhf(cn);
            c_st[idx] = cn;
            h_out[idx] = hn;
        }
    }
}

// Halting state machine: z = h2n . w_halt + b_halt, per-row ACT update.
__global__ __launch_bounds__(256) void k_halt(
    const float* __restrict__ h2n, const float* __restrict__ Whalt,
    const float* __restrict__ bhalt, float* __restrict__ halt,
    float* __restrict__ cont, float* __restrict__ coef,
    float* __restrict__ ponder_out, unsigned* __restrict__ ctrl,
    const unsigned* __restrict__ cnt_prev, int step)
{
    if (step > 0 && cnt_prev[0] == 0u) return;
    const int lane = threadIdx.x & 63;
    const int b = blockIdx.x * 4 + (threadIdx.x >> 6);
    const float* hrow = h2n + (size_t)b * 1024;
    float sum = 0.0f;
    for (int k = lane; k < 1024; k += 64) sum += hrow[k] * Whalt[k];
#pragma unroll
    for (int off = 32; off > 0; off >>= 1) sum += __shfl_down(sum, off, 64);
    if (lane == 0) {
        const float z = sum + bhalt[0];
        const float sh = sigmoidf_(z);
        float co = 0.0f;
        if (cont[b] != 0.0f) {
            const float hn = halt[b] + sh;
            const bool ending = hn > 0.99f;
            co = sh + (ending ? (1.0f - hn) : 0.0f);
            halt[b] = hn;
            if (!ending) {
                cont[b] = 1.0f;
                ponder_out[b] += 1.0f;
                atomicAdd(&ctrl[step], 1u);
            } else {
                cont[b] = 0.0f;
            }
        }
        coef[b] = co;
        if (b == 0) ctrl[12] = (unsigned)(step + 1);
    }
}

// acc_out += coef * h2n for rows with coef != 0
__global__ __launch_bounds__(256) void k_accum(
    const float* __restrict__ h2n, const float* __restrict__ coef,
    float* __restrict__ acc_out, const unsigned* __restrict__ cnt_prev, int step)
{
    if (step > 0 && cnt_prev[0] == 0u) return;
    const int b = blockIdx.x;
    const float co = coef[b];
    if (co == 0.0f) return;
    const float4* src = (const float4*)(h2n + (size_t)b * 1024);
    float4* dst = (float4*)(acc_out + (size_t)b * 1024);
    const int i = threadIdx.x;  // 256 float4 = 1024 floats
    float4 d = dst[i];
    const float4 s = src[i];
    d.x = fmaf(co, s.x, d.x); d.y = fmaf(co, s.y, d.y);
    d.z = fmaf(co, s.z, d.z); d.w = fmaf(co, s.w, d.w);
    dst[i] = d;
}

__global__ __launch_bounds__(256) void k_small_init(
    float* __restrict__ halt, float* __restrict__ cont,
    float* __restrict__ ponder_out, unsigned* __restrict__ ctrl)
{
    const int b = blockIdx.x * 256 + threadIdx.x;
    if (b < 4096) {
        halt[b] = 0.0f;
        cont[b] = 1.0f;
        ponder_out[b] = 0.0f;
    }
    if (b < 16) ctrl[b] = 0u;
}

// copy final states to d_out + remainder term for still-continuing rows
__global__ __launch_bounds__(256) void k_fin1(
    const float* __restrict__ h1a, const float* __restrict__ h1b,
    const float* __restrict__ h2a, const float* __restrict__ h2b,
    const float* __restrict__ c1s, const float* __restrict__ c2s,
    const float* __restrict__ halt, const float* __restrict__ cont,
    const unsigned* __restrict__ ctrl, float* __restrict__ out)
{
    const int par = (int)(ctrl[12] & 1u);
    const float* h1f = par ? h1b : h1a;
    const float* h2f = par ? h2b : h2a;
    const int b = blockIdx.x;
    const float rem = (cont[b] != 0.0f) ? (1.0f - halt[b]) : 0.0f;
    const int base = b * 1024;
    for (int i = threadIdx.x; i < 1024; i += 256) {
        const float h2v = h2f[base + i];
        out[O_H1 + base + i] = h1f[base + i];
        out[O_C1 + base + i] = c1s[base + i];
        out[O_H2 + base + i] = h2v;
        out[O_C2 + base + i] = c2s[base + i];
        if (rem != 0.0f) out[O_ACC + base + i] += rem * h2v;
    }
}

// ponder_cost = -0.01 * mean(halt_accum)   (acc_rem == halt_accum identically)
__global__ __launch_bounds__(256) void k_fin2(
    const float* __restrict__ halt, float* __restrict__ out)
{
    __shared__ float red[256];
    float s = 0.0f;
    for (int i = threadIdx.x; i < 4096; i += 256) s += halt[i];
    red[threadIdx.x] = s;
    __syncthreads();
    for (int w = 128; w > 0; w >>= 1) {
        if (threadIdx.x < w) red[threadIdx.x] += red[threadIdx.x + w];
        __syncthreads();
    }
    if (threadIdx.x == 0) out[O_PCOST] = -0.01f * (red[0] * (1.0f / 4096.0f));
}

extern "C" void kernel_launch(void* const* d_in, const int* in_sizes, int n_in,
                              void* d_out, int out_size, void* d_ws, size_t ws_size,
                              hipStream_t stream) {
    const float* inputs = (const float*)d_in[0];
    const float* W_ih1  = (const float*)d_in[1];
    const float* W_hh1  = (const float*)d_in[2];
    const float* b_ih1  = (const float*)d_in[3];
    const float* b_hh1  = (const float*)d_in[4];
    const float* W_ih2  = (const float*)d_in[5];
    const float* W_hh2  = (const float*)d_in[6];
    const float* b_ih2  = (const float*)d_in[7];
    const float* b_hh2  = (const float*)d_in[8];
    const float* W_halt = (const float*)d_in[9];
    const float* b_halt = (const float*)d_in[10];

    float* out = (float*)d_out;
    float* Z1  = out + O_H1;          // 64 MB spanning h1..c2 regions
    float* ws  = (float*)d_ws;

    float* act  = ws + ACT_OFS;
    float* h1a  = ws + H1A_OFS;
    float* h1b  = ws + H1B_OFS;
    float* h2a  = ws + H2A_OFS;
    float* h2b  = ws + H2B_OFS;
    float* c1s  = ws + C1_OFS;
    float* c2s  = ws + C2_OFS;
    float* halt = ws + HALT_OFS;
    float* cont = ws + CONT_OFS;
    float* coef = ws + COEF_OFS;
    unsigned* ctrl = (unsigned*)(ws + CTRL_OFS);

    const size_t mb16 = (size_t)BATCH * HDIM * sizeof(float);
    hipMemsetAsync(out + O_ACC, 0, mb16, stream);
    hipMemsetAsync(h1a, 0, mb16, stream);
    hipMemsetAsync(h2a, 0, mb16, stream);
    hipMemsetAsync(c1s, 0, mb16, stream);
    hipMemsetAsync(c2s, 0, mb16, stream);
    k_small_init<<<16, 256, 0, stream>>>(halt, cont, out + O_PSTEP, ctrl);

    const dim3 ggrid(64, 16);
    k_z1<<<ggrid, 256, 0, stream>>>(inputs, W_ih1, b_ih1, b_hh1, Z1);

    for (int s = 0; s < TSTEPS; ++s) {
        float* h1in  = (s & 1) ? h1b : h1a;
        float* h1out = (s & 1) ? h1a : h1b;
        float* h2in  = (s & 1) ? h2b : h2a;
        float* h2out = (s & 1) ? h2a : h2b;
        const unsigned* cnt_prev = ctrl + (s > 0 ? s - 1 : 0);

        k_stepA<<<ggrid, 256, 0, stream>>>(Z1, W_hh1, W_ih1, h1in, c1s, h1out, act,
                                           cnt_prev, s);
        k_stepB<<<ggrid, 256, 0, stream>>>(act, W_ih2, W_hh2, b_ih2, b_hh2, h2in,
                                           c2s, h2out, cnt_prev, s);
        k_halt<<<1024, 256, 0, stream>>>(h2out, W_halt, b_halt, halt, cont, coef,
                                         out + O_PSTEP, ctrl, cnt_prev, s);
        k_accum<<<4096, 256, 0, stream>>>(h2out, coef, out + O_ACC, cnt_prev, s);
    }

    k_fin1<<<4096, 256, 0, stream>>>(h1a, h1b, h2a, h2b, c1s, c2s, halt, cont, ctrl, out);
    k_fin2<<<1, 256, 0, stream>>>(halt, out);
}

// Round 2
// 3007.299 us; speedup vs baseline: 1.8404x; 1.8404x over previous
//
#include <hip/hip_runtime.h>
#include <cstdint>
#include <cstddef>

// ---------------------------------------------------------------------------
// AdaptiveLSTMBlockWrapper — ACT ponder loop, round 2: split-f16 MFMA GEMMs.
//
// fp32 GEMM emulated as 3 f16 MFMA products (hi/lo split, fp32 accumulate):
//   A*B ~= Ah*Bh + Ah*Bl + Al*Bh   (residual ~2^-23 relative, fp32-class)
//
// - Activations (h1, h2, act) stored as PRE-SPLIT f16 hi/lo pairs, written by
//   the fused LSTM epilogues; GEMM stages them as pass-through 16B chunks.
// - Weights stay fp32 in d_in; reg-staged + split on the fly (overlaps MFMA).
// - Tile: 128 rows x 128 virtual cols (4 gates x 32 h-cols), 4 waves (2x2),
//   BK=64, XOR-swizzled LDS rows -> conflict-free ds_read_b128 fragments.
// - Z1 = x@Wih1[: , :1024]^T + b_ih1 + b_hh1 precomputed once (fp32, lives in
//   d_out's h1..c2 regions until finalize). Flag column added at step 0 only.
// - Step 0: h1=h2=0 -> stepA skips its GEMM, stepB skips the Whh2 pass.
// - ws usage ~112 MB (proven >=117.5 available in round 1).
// ---------------------------------------------------------------------------

typedef _Float16 f16;
typedef f16   f16x8 __attribute__((ext_vector_type(8)));
typedef f16   f16x4 __attribute__((ext_vector_type(4)));
typedef float f32x4 __attribute__((ext_vector_type(4)));

#define TSTEPS 12

// d_out layout (float offsets)
#define O_ACC   0u
#define O_H1    4194304u
#define O_C1    8388608u
#define O_H2    12582912u
#define O_C2    16777216u
#define O_PCOST 20971520u
#define O_PSTEP 20971521u

// LDS tile byte offsets (4 x 16 KB = 64 KB)
#define OFF_AHI 0
#define OFF_ALO 16384
#define OFF_BHI 32768
#define OFF_BLO 49152

__device__ __forceinline__ float sigmoidf_(float x) { return 1.0f / (1.0f + expf(-x)); }

// ---------------------------------------------------------------------------
// Core pass: acc += A(128 rows x K=1024) * B(128 vcols x K)^T for one K=1024
// sweep. A either pre-split f16 pairs (A_PAIR) or fp32 (split on the fly).
// B fp32, rows gathered via the gate-permuted mapping (done by caller via
// hc0); stride 1024 (aligned float4) or 1025 (scalar loads, z1 only).
// LDS rows are 128 B with slot16 ^= (row&7) XOR swizzle (conflict-free).
// ---------------------------------------------------------------------------
template<bool A_PAIR, bool B_ALIGNED>
__device__ __forceinline__ void gemm_pass(
    const f16* __restrict__ Ahi, const f16* __restrict__ Alo,
    const float* __restrict__ Af32,
    const float* __restrict__ Bw, int bstride,
    int m0, int hc0, f32x4 (&acc)[4][4], char* sm)
{
    const int tid  = threadIdx.x;
    const int lane = tid & 63;
    const int wid  = tid >> 6;
    const int wr0  = (wid >> 1) * 64;   // wave row stripe
    const int cs   = wid & 1;           // wave col stripe
    const int l15  = lane & 15;
    const int lk   = lane >> 4;

    // B staging: thread -> (LDS row blv, k-half). Weight row via gate-permuted
    // mapping: lv = cs*64 + g*16 + hcl  <->  wrow = g*1024 + hc0 + cs*16 + hcl
    const int blv  = tid >> 1;
    const int bkh  = (tid & 1) * 32;
    const int brow = ((blv >> 4) & 3) * 1024 + hc0 + (blv >> 6) * 16 + (blv & 15);
    const float* bsrc = Bw + (size_t)brow * bstride;

    float4 bv[8];
    int4   pah[4], pal[4];
    float4 av[8];

    auto do_loads = [&](int kt) {
#pragma unroll
        for (int i = 0; i < 8; ++i) {
            const float* p = bsrc + kt * 64 + bkh + i * 4;
            if constexpr (B_ALIGNED) bv[i] = *(const float4*)p;
            else { bv[i].x = p[0]; bv[i].y = p[1]; bv[i].z = p[2]; bv[i].w = p[3]; }
        }
        if constexpr (A_PAIR) {
#pragma unroll
            for (int j = 0; j < 4; ++j) {
                const int c = tid + 256 * j;
                const int row = c >> 3, sl = c & 7;
                const size_t g = (size_t)(m0 + row) * 1024 + kt * 64 + sl * 8;
                pah[j] = *(const int4*)(Ahi + g);
                pal[j] = *(const int4*)(Alo + g);
            }
        } else {
#pragma unroll
            for (int i = 0; i < 8; ++i)
                av[i] = *(const float4*)(Af32 + (size_t)(m0 + blv) * 1024 + kt * 64 + bkh + i * 4);
        }
    };

    // split one float4 and write hi/lo 8B halves at the swizzled slot
    auto split_write = [&](int base_hi, int base_lo, int row, const float4& v, int i) {
        const f16 s0 = (f16)v.x, s1 = (f16)v.y, s2 = (f16)v.z, s3 = (f16)v.w;
        const f16x4 hv = {s0, s1, s2, s3};
        const f16x4 lw = {(f16)(v.x - (float)s0), (f16)(v.y - (float)s1),
                          (f16)(v.z - (float)s2), (f16)(v.w - (float)s3)};
        const int kslot = (tid & 1) * 4 + (i >> 1);
        const int off = row * 128 + ((kslot ^ (row & 7)) << 4) + (i & 1) * 8;
        *(f16x4*)(sm + base_hi + off) = hv;
        *(f16x4*)(sm + base_lo + off) = lw;
    };

    auto do_writes = [&]() {
#pragma unroll
        for (int i = 0; i < 8; ++i) split_write(OFF_BHI, OFF_BLO, blv, bv[i], i);
        if constexpr (A_PAIR) {
#pragma unroll
            for (int j = 0; j < 4; ++j) {
                const int c = tid + 256 * j;
                const int row = c >> 3, sl = c & 7;
                const int off = row * 128 + ((sl ^ (row & 7)) << 4);
                *(int4*)(sm + OFF_AHI + off) = pah[j];
                *(int4*)(sm + OFF_ALO + off) = pal[j];
            }
        } else {
#pragma unroll
            for (int i = 0; i < 8; ++i) split_write(OFF_AHI, OFF_ALO, blv, av[i], i);
        }
    };

    auto compute = [&]() {
#pragma unroll
        for (int ks = 0; ks < 2; ++ks) {
            f16x8 ah[4], al[4];
#pragma unroll
            for (int mf = 0; mf < 4; ++mf) {
                const int row = wr0 + mf * 16 + l15;
                const int off = row * 128 + ((((ks << 2) + lk) ^ (row & 7)) << 4);
                ah[mf] = *(const f16x8*)(sm + OFF_AHI + off);
                al[mf] = *(const f16x8*)(sm + OFF_ALO + off);
            }
#pragma unroll
            for (int g = 0; g < 4; ++g) {
                const int lv  = cs * 64 + g * 16 + l15;
                const int off = lv * 128 + ((((ks << 2) + lk) ^ (lv & 7)) << 4);
                const f16x8 bh = *(const f16x8*)(sm + OFF_BHI + off);
                const f16x8 bl = *(const f16x8*)(sm + OFF_BLO + off);
#pragma unroll
                for (int mf = 0; mf < 4; ++mf) {
                    acc[mf][g] = __builtin_amdgcn_mfma_f32_16x16x32_f16(ah[mf], bh, acc[mf][g], 0, 0, 0);
                    acc[mf][g] = __builtin_amdgcn_mfma_f32_16x16x32_f16(ah[mf], bl, acc[mf][g], 0, 0, 0);
                    acc[mf][g] = __builtin_amdgcn_mfma_f32_16x16x32_f16(al[mf], bh, acc[mf][g], 0, 0, 0);
                }
            }
        }
    };

    do_loads(0);
    for (int kt = 0; kt < 16; ++kt) {
        __syncthreads();                 // prior tile's reads complete
        do_writes();
        __syncthreads();
        if (kt < 15) do_loads(kt + 1);   // latency hides under MFMA below
        compute();
    }
}

__device__ __forceinline__ void block_tile(int& m0, int& hc0) {
    const int bid = blockIdx.x;
    const int lid = (bid & 7) * 128 + (bid >> 3);   // XCD-contiguous chunks
    m0  = (lid >> 5) * 128;
    hc0 = (lid & 31) * 32;
}

// Z1 = x @ W_ih1[:, :1024]^T + b_ih1 + b_hh1  (W_ih1 stride 1025 -> scalar B)
__global__ __launch_bounds__(256) void k_z1(
    const float* __restrict__ x, const float* __restrict__ Wih1,
    const float* __restrict__ bih1, const float* __restrict__ bhh1,
    float* __restrict__ Z1)
{
    __shared__ __align__(16) char sm[65536];
    int m0, hc0; block_tile(m0, hc0);
    f32x4 acc[4][4];
#pragma unroll
    for (int a = 0; a < 4; ++a)
#pragma unroll
        for (int b = 0; b < 4; ++b) acc[a][b] = (f32x4){0.f, 0.f, 0.f, 0.f};
    gemm_pass<false, false>(nullptr, nullptr, x, Wih1, 1025, m0, hc0, acc, sm);

    const int tid = threadIdx.x, lane = tid & 63, wid = tid >> 6;
    const int wr0 = (wid >> 1) * 64, cs = wid & 1, l15 = lane & 15, lk = lane >> 4;
#pragma unroll
    for (int mf = 0; mf < 4; ++mf)
#pragma unroll
        for (int r = 0; r < 4; ++r) {
            const int row = m0 + wr0 + mf * 16 + lk * 4 + r;
            const int hc  = hc0 + cs * 16 + l15;
#pragma unroll
            for (int g = 0; g < 4; ++g) {
                const int R = g * 1024 + hc;
                Z1[(size_t)row * 4096 + R] = acc[mf][g][r] + bih1[R] + bhh1[R];
            }
        }
}

// Layer-1 cell: gates = Z1 (+flag col @step0) + h1@Whh1^T -> c1,h1 pair,act pair
__global__ __launch_bounds__(256) void k_stepA(
    const float* __restrict__ Z1, const float* __restrict__ Whh1,
    const float* __restrict__ Wih1,
    const f16* __restrict__ h1hi_in, const f16* __restrict__ h1lo_in,
    float* __restrict__ c1,
    f16* __restrict__ h1hi_out, f16* __restrict__ h1lo_out,
    f16* __restrict__ acthi, f16* __restrict__ actlo,
    const unsigned* __restrict__ cnt_prev, int step)
{
    if (step > 0 && cnt_prev[0] == 0u) return;
    __shared__ __align__(16) char sm[65536];
    int m0, hc0; block_tile(m0, hc0);
    f32x4 acc[4][4];
#pragma unroll
    for (int a = 0; a < 4; ++a)
#pragma unroll
        for (int b = 0; b < 4; ++b) acc[a][b] = (f32x4){0.f, 0.f, 0.f, 0.f};
    if (step > 0)
        gemm_pass<true, true>(h1hi_in, h1lo_in, nullptr, Whh1, 1024, m0, hc0, acc, sm);

    const int tid = threadIdx.x, lane = tid & 63, wid = tid >> 6;
    const int wr0 = (wid >> 1) * 64, cs = wid & 1, l15 = lane & 15, lk = lane >> 4;
#pragma unroll
    for (int mf = 0; mf < 4; ++mf)
#pragma unroll
        for (int r = 0; r < 4; ++r) {
            const int row = m0 + wr0 + mf * 16 + lk * 4 + r;
            const int hc  = hc0 + cs * 16 + l15;
            float p[4];
#pragma unroll
            for (int g = 0; g < 4; ++g) {
                p[g] = acc[mf][g][r] + Z1[(size_t)row * 4096 + g * 1024 + hc];
                if (step == 0) p[g] += Wih1[(size_t)(g * 1024 + hc) * 1025 + 1024];
            }
            const float ig = sigmoidf_(p[0]);
            const float fg = sigmoidf_(p[1]);
            const float gg = tanhf(p[2]);
            const float og = sigmoidf_(p[3]);
            const int idx = row * 1024 + hc;
            const float cn = fg * c1[idx] + ig * gg;
            c1[idx] = cn;
            const float h = og * tanhf(cn);
            const f16 hh = (f16)h;
            const f16 hl = (f16)(h - (float)hh);
            h1hi_out[idx] = hh; h1lo_out[idx] = hl;
            const bool pos = h > 0.0f;
            acthi[idx] = pos ? hh : (f16)0.0f;
            actlo[idx] = pos ? hl : (f16)0.0f;
        }
}

// Layer-2 cell: gates = b2 + act@Wih2^T + h2@Whh2^T -> c2, h2 pair
__global__ __launch_bounds__(256) void k_stepB(
    const f16* __restrict__ acthi, const f16* __restrict__ actlo,
    const float* __restrict__ Wih2,
    const f16* __restrict__ h2hi_in, const f16* __restrict__ h2lo_in,
    const float* __restrict__ Whh2,
    const float* __restrict__ bih2, const float* __restrict__ bhh2,
    float* __restrict__ c2, f16* __restrict__ h2hi_out, f16* __restrict__ h2lo_out,
    const unsigned* __restrict__ cnt_prev, int step)
{
    if (step > 0 && cnt_prev[0] == 0u) return;
    __shared__ __align__(16) char sm[65536];
    int m0, hc0; block_tile(m0, hc0);
    f32x4 acc[4][4];
#pragma unroll
    for (int a = 0; a < 4; ++a)
#pragma unroll
        for (int b = 0; b < 4; ++b) acc[a][b] = (f32x4){0.f, 0.f, 0.f, 0.f};
    gemm_pass<true, true>(acthi, actlo, nullptr, Wih2, 1024, m0, hc0, acc, sm);
    if (step > 0)
        gemm_pass<true, true>(h2hi_in, h2lo_in, nullptr, Whh2, 1024, m0, hc0, acc, sm);

    const int tid = threadIdx.x, lane = tid & 63, wid = tid >> 6;
    const int wr0 = (wid >> 1) * 64, cs = wid & 1, l15 = lane & 15, lk = lane >> 4;
#pragma unroll
    for (int mf = 0; mf < 4; ++mf)
#pragma unroll
        for (int r = 0; r < 4; ++r) {
            const int row = m0 + wr0 + mf * 16 + lk * 4 + r;
            const int hc  = hc0 + cs * 16 + l15;
            float p[4];
#pragma unroll
            for (int g = 0; g < 4; ++g) {
                const int R = g * 1024 + hc;
                p[g] = acc[mf][g][r] + bih2[R] + bhh2[R];
            }
            const float ig = sigmoidf_(p[0]);
            const float fg = sigmoidf_(p[1]);
            const float gg = tanhf(p[2]);
            const float og = sigmoidf_(p[3]);
            const int idx = row * 1024 + hc;
            const float cn = fg * c2[idx] + ig * gg;
            c2[idx] = cn;
            const float h = og * tanhf(cn);
            const f16 hh = (f16)h;
            h2hi_out[idx] = hh;
            h2lo_out[idx] = (f16)(h - (float)hh);
        }
}

// Halting state machine (one wave per row; h2 reconstructed from pair)
__global__ __launch_bounds__(256) void k_halt(
    const f16* __restrict__ h2hi, const f16* __restrict__ h2lo,
    const float* __restrict__ Whalt, const float* __restrict__ bhalt,
    float* __restrict__ halt, float* __restrict__ cont, float* __restrict__ coef,
    float* __restrict__ ponder_out, unsigned* __restrict__ ctrl,
    const unsigned* __restrict__ cnt_prev, int step)
{
    if (step > 0 && cnt_prev[0] == 0u) return;
    const int lane = threadIdx.x & 63;
    const int b = blockIdx.x * 4 + (threadIdx.x >> 6);
    const size_t base = (size_t)b * 1024;
    float sum = 0.0f;
    for (int k = lane; k < 1024; k += 64)
        sum += ((float)h2hi[base + k] + (float)h2lo[base + k]) * Whalt[k];
#pragma unroll
    for (int off = 32; off > 0; off >>= 1) sum += __shfl_down(sum, off, 64);
    if (lane == 0) {
        const float sh = sigmoidf_(sum + bhalt[0]);
        float co = 0.0f;
        if (cont[b] != 0.0f) {
            const float hn = halt[b] + sh;
            const bool ending = hn > 0.99f;
            co = sh + (ending ? (1.0f - hn) : 0.0f);
            halt[b] = hn;
            if (!ending) {
                ponder_out[b] += 1.0f;
                atomicAdd(&ctrl[step], 1u);
            } else {
                cont[b] = 0.0f;
            }
        }
        coef[b] = co;
        if (b == 0) ctrl[12] = (unsigned)(step + 1);
    }
}

// acc_out += coef * h2 for rows with coef != 0
__global__ __launch_bounds__(256) void k_accum(
    const f16* __restrict__ h2hi, const f16* __restrict__ h2lo,
    const float* __restrict__ coef, float* __restrict__ acc_out,
    const unsigned* __restrict__ cnt_prev, int step)
{
    if (step > 0 && cnt_prev[0] == 0u) return;
    const int b = blockIdx.x;
    const float co = coef[b];
    if (co == 0.0f) return;
    const size_t base = (size_t)b * 1024;
    const int i = threadIdx.x;          // 256 threads x 4 floats
    const f16x4 hv = *(const f16x4*)(h2hi + base + i * 4);
    const f16x4 lv = *(const f16x4*)(h2lo + base + i * 4);
    float4* dst = (float4*)(acc_out + base);
    float4 d = dst[i];
    d.x = fmaf(co, (float)hv[0] + (float)lv[0], d.x);
    d.y = fmaf(co, (float)hv[1] + (float)lv[1], d.y);
    d.z = fmaf(co, (float)hv[2] + (float)lv[2], d.z);
    d.w = fmaf(co, (float)hv[3] + (float)lv[3], d.w);
    dst[i] = d;
}

__global__ __launch_bounds__(256) void k_small_init(
    float* __restrict__ halt, float* __restrict__ cont,
    float* __restrict__ ponder_out, unsigned* __restrict__ ctrl)
{
    const int b = blockIdx.x * 256 + threadIdx.x;
    if (b < 4096) { halt[b] = 0.0f; cont[b] = 1.0f; ponder_out[b] = 0.0f; }
    if (b < 16) ctrl[b] = 0u;
}

// finalize: states to d_out + remainder term for still-continuing rows
__global__ __launch_bounds__(256) void k_fin1(
    const f16* __restrict__ h1hi0, const f16* __restrict__ h1hi1,
    const f16* __restrict__ h1lo0, const f16* __restrict__ h1lo1,
    const f16* __restrict__ h2hi0, const f16* __restrict__ h2hi1,
    const f16* __restrict__ h2lo0, const f16* __restrict__ h2lo1,
    const float* __restrict__ c1s, const float* __restrict__ c2s,
    const float* __restrict__ halt, const float* __restrict__ cont,
    const unsigned* __restrict__ ctrl, float* __restrict__ out)
{
    const int par = (int)(ctrl[12] & 1u);
    const f16* h1h = par ? h1hi1 : h1hi0;
    const f16* h1l = par ? h1lo1 : h1lo0;
    const f16* h2h = par ? h2hi1 : h2hi0;
    const f16* h2l = par ? h2lo1 : h2lo0;
    const int b = blockIdx.x;
    const float rem = (cont[b] != 0.0f) ? (1.0f - halt[b]) : 0.0f;
    const int base = b * 1024;
    for (int i = threadIdx.x; i < 1024; i += 256) {
        const float h1v = (float)h1h[base + i] + (float)h1l[base + i];
        const float h2v = (float)h2h[base + i] + (float)h2l[base + i];
        out[O_H1 + base + i] = h1v;
        out[O_C1 + base + i] = c1s[base + i];
        out[O_H2 + base + i] = h2v;
        out[O_C2 + base + i] = c2s[base + i];
        if (rem != 0.0f) out[O_ACC + base + i] += rem * h2v;
    }
}

__global__ __launch_bounds__(256) void k_fin2(
    const float* __restrict__ halt, float* __restrict__ out)
{
    __shared__ float red[256];
    float s = 0.0f;
    for (int i = threadIdx.x; i < 4096; i += 256) s += halt[i];
    red[threadIdx.x] = s;
    __syncthreads();
    for (int w = 128; w > 0; w >>= 1) {
        if (threadIdx.x < w) red[threadIdx.x] += red[threadIdx.x + w];
        __syncthreads();
    }
    if (threadIdx.x == 0) out[O_PCOST] = -0.01f * (red[0] * (1.0f / 4096.0f));
}

extern "C" void kernel_launch(void* const* d_in, const int* in_sizes, int n_in,
                              void* d_out, int out_size, void* d_ws, size_t ws_size,
                              hipStream_t stream) {
    const float* inputs = (const float*)d_in[0];
    const float* W_ih1  = (const float*)d_in[1];
    const float* W_hh1  = (const float*)d_in[2];
    const float* b_ih1  = (const float*)d_in[3];
    const float* b_hh1  = (const float*)d_in[4];
    const float* W_ih2  = (const float*)d_in[5];
    const float* W_hh2  = (const float*)d_in[6];
    const float* b_ih2  = (const float*)d_in[7];
    const float* b_hh2  = (const float*)d_in[8];
    const float* W_halt = (const float*)d_in[9];
    const float* b_halt = (const float*)d_in[10];

    float* out = (float*)d_out;
    float* Z1  = out + O_H1;                       // 64 MB in d_out h1..c2 regions

    char* wsb = (char*)d_ws;
    float* c1s = (float*)(wsb);
    float* c2s = (float*)(wsb + (16u << 20));
    f16* h1hi[2] = { (f16*)(wsb + (32u << 20)), (f16*)(wsb + (40u << 20)) };
    f16* h1lo[2] = { (f16*)(wsb + (48u << 20)), (f16*)(wsb + (56u << 20)) };
    f16* h2hi[2] = { (f16*)(wsb + (64u << 20)), (f16*)(wsb + (72u << 20)) };
    f16* h2lo[2] = { (f16*)(wsb + (80u << 20)), (f16*)(wsb + (88u << 20)) };
    f16* acthi   = (f16*)(wsb + (96u << 20));
    f16* actlo   = (f16*)(wsb + (104u << 20));
    float* halt  = (float*)(wsb + (112u << 20));
    float* cont  = halt + 4096;
    float* coef  = cont + 4096;
    unsigned* ctrl = (unsigned*)(coef + 4096);

    const size_t mb16 = (size_t)4096 * 1024 * sizeof(float);
    hipMemsetAsync(out + O_ACC, 0, mb16, stream);
    hipMemsetAsync(c1s, 0, mb16, stream);
    hipMemsetAsync(c2s, 0, mb16, stream);
    k_small_init<<<16, 256, 0, stream>>>(halt, cont, out + O_PSTEP, ctrl);

    k_z1<<<1024, 256, 0, stream>>>(inputs, W_ih1, b_ih1, b_hh1, Z1);

    for (int s = 0; s < TSTEPS; ++s) {
        const int wsel = (s & 1) ? 0 : 1;          // write set (s even -> set1)
        const int rsel = 1 - wsel;
        const unsigned* cnt_prev = ctrl + (s > 0 ? s - 1 : 0);

        k_stepA<<<1024, 256, 0, stream>>>(Z1, W_hh1, W_ih1,
                                          h1hi[rsel], h1lo[rsel], c1s,
                                          h1hi[wsel], h1lo[wsel], acthi, actlo,
                                          cnt_prev, s);
        k_stepB<<<1024, 256, 0, stream>>>(acthi, actlo, W_ih2,
                                          h2hi[rsel], h2lo[rsel], W_hh2,
                                          b_ih2, b_hh2, c2s,
                                          h2hi[wsel], h2lo[wsel],
                                          cnt_prev, s);
        k_halt<<<1024, 256, 0, stream>>>(h2hi[wsel], h2lo[wsel], W_halt, b_halt,
                                         halt, cont, coef, out + O_PSTEP, ctrl,
                                         cnt_prev, s);
        k_accum<<<4096, 256, 0, stream>>>(h2hi[wsel], h2lo[wsel], coef,
                                          out + O_ACC, cnt_prev, s);
    }

    k_fin1<<<4096, 256, 0, stream>>>(h1hi[0], h1hi[1], h1lo[0], h1lo[1],
                                     h2hi[0], h2hi[1], h2lo[0], h2lo[1],
                                     c1s, c2s, halt, cont, ctrl, out);
    k_fin2<<<1, 256, 0, stream>>>(halt, out);
}

// Round 3
// 1635.611 us; speedup vs baseline: 3.3838x; 1.8386x over previous
//
#include <hip/hip_runtime.h>
#include <cstdint>
#include <cstddef>

// ---------------------------------------------------------------------------
// AdaptiveLSTMBlockWrapper — round 3: glds pass-through staging of pre-split
// f16 pairs. fp32 GEMM = 3-product split-f16 MFMA (Ah*Bh + Ah*Bl + Al*Bh).
//
// - Weights Wih1', Wih2, Whh2 and input x pre-split ONCE per call into f16
//   hi/lo pairs living in d_out's state region (dead until k_fin1).
// - GEMM staging via __builtin_amdgcn_global_load_lds(16B): linear LDS dest,
//   per-lane inverse-swizzled global source; reads use slot^(row&7) swizzle
//   (both-sides-or-neither, rule 21). Same XOR layout as proven round 2.
// - stepA: glds-pass (x@Wih1) + mixed-pass (h1@Whh1: B fp32 reg-split, no ws
//   room for Whh1 pairs). stepB: two pure glds passes.
// - XCD-major hc mapping: per-XCD weight slab 2MB -> L2-resident.
// ---------------------------------------------------------------------------

typedef _Float16 f16;
typedef f16   f16x8 __attribute__((ext_vector_type(8)));
typedef f16   f16x4 __attribute__((ext_vector_type(4)));
typedef float f32x4 __attribute__((ext_vector_type(4)));

#define TSTEPS 12

// d_out float offsets (outputs)
#define O_ACC   0u
#define O_H1    4194304u
#define O_C1    8388608u
#define O_H2    12582912u
#define O_C2    16777216u
#define O_PCOST 20971520u
#define O_PSTEP 20971521u
// d_out byte offsets for pair buffers (inside the [16MiB,80MiB) state region)
#define DO_W1HI (16u<<20)
#define DO_W1LO (24u<<20)
#define DO_W2HI (32u<<20)
#define DO_W2LO (40u<<20)
#define DO_W3HI (48u<<20)
#define DO_W3LO (56u<<20)
#define DO_XHI  (64u<<20)
#define DO_XLO  (72u<<20)

// ws byte offsets
#define WS_C1    (size_t)(0u)
#define WS_C2    ((size_t)16u<<20)
#define WS_H1HI0 ((size_t)32u<<20)
#define WS_H1HI1 ((size_t)40u<<20)
#define WS_H1LO0 ((size_t)48u<<20)
#define WS_H1LO1 ((size_t)56u<<20)
#define WS_H2HI0 ((size_t)64u<<20)
#define WS_H2HI1 ((size_t)72u<<20)
#define WS_H2LO0 ((size_t)80u<<20)
#define WS_H2LO1 ((size_t)88u<<20)
#define WS_ACTHI ((size_t)96u<<20)
#define WS_ACTLO ((size_t)104u<<20)
#define WS_MISC  ((size_t)112u<<20)

// LDS buffer byte offsets (4 x 16KB; rows are 128B = 8 slots of 16B)
#define OFF_AHI 0
#define OFF_ALO 16384
#define OFF_BHI 32768
#define OFF_BLO 49152

__device__ __forceinline__ float sigmoidf_(float x) { return 1.0f / (1.0f + expf(-x)); }

__device__ __forceinline__ void glds16(const void* g, void* l) {
    __builtin_amdgcn_global_load_lds(
        (const __attribute__((address_space(1))) unsigned int*)g,
        (__attribute__((address_space(3))) unsigned int*)l, 16, 0, 0);
}

// LDS content invariant: buf[r][s] = k-chunk (s ^ (r&7)) of logical row r.
// Read chunk c of row r at slot c ^ (r&7).
__device__ __forceinline__ void tile_compute(char* sm, f32x4 (&acc)[4][4],
                                             int wr0, int cs, int l15, int lk)
{
#pragma unroll
    for (int ks = 0; ks < 2; ++ks) {
        f16x8 ah[4], al[4];
#pragma unroll
        for (int mf = 0; mf < 4; ++mf) {
            const int row = wr0 + mf * 16 + l15;
            const int off = row * 128 + ((((ks << 2) + lk) ^ (row & 7)) << 4);
            ah[mf] = *(const f16x8*)(sm + OFF_AHI + off);
            al[mf] = *(const f16x8*)(sm + OFF_ALO + off);
        }
#pragma unroll
        for (int g = 0; g < 4; ++g) {
            const int lv  = cs * 64 + g * 16 + l15;
            const int off = lv * 128 + ((((ks << 2) + lk) ^ (lv & 7)) << 4);
            const f16x8 bh = *(const f16x8*)(sm + OFF_BHI + off);
            const f16x8 bl = *(const f16x8*)(sm + OFF_BLO + off);
#pragma unroll
            for (int mf = 0; mf < 4; ++mf) {
                acc[mf][g] = __builtin_amdgcn_mfma_f32_16x16x32_f16(ah[mf], bh, acc[mf][g], 0, 0, 0);
                acc[mf][g] = __builtin_amdgcn_mfma_f32_16x16x32_f16(ah[mf], bl, acc[mf][g], 0, 0, 0);
                acc[mf][g] = __builtin_amdgcn_mfma_f32_16x16x32_f16(al[mf], bh, acc[mf][g], 0, 0, 0);
            }
        }
    }
}

// Full-glds pass: A pairs [4096][1024] f16 rows m0..m0+127; B pairs are weight
// rows Wmap(lv) = ((lv>>4)&3)*1024 + hc0 + (lv>>6)*16 + (lv&15).
// Wave w stages buffer w: 16 glds of 1KB; lane l covers (r = i*8 + (l>>3),
// s = l&7), global chunk s^(l>>3)  [r&7 == l>>3 since i*8 ≡ 0 mod 8].
__device__ __forceinline__ void pass_glds(
    const f16* __restrict__ Ahi, const f16* __restrict__ Alo,
    const f16* __restrict__ Bhi, const f16* __restrict__ Blo,
    int m0, int hc0, f32x4 (&acc)[4][4], char* sm, bool first)
{
    const int tid = threadIdx.x, lane = tid & 63, wid = tid >> 6;
    const int wr0 = (wid >> 1) * 64, cs = wid & 1, l15 = lane & 15, lk = lane >> 4;
    const int rl = lane >> 3, sl = lane & 7;
    const int swz = (sl ^ rl) << 3;   // f16 elements within the 128B k-window

    const f16* gsrc;
    int lbase;
    if (wid == 0)      { gsrc = Ahi + (size_t)(m0 + rl) * 1024 + swz; lbase = OFF_AHI; }
    else if (wid == 1) { gsrc = Alo + (size_t)(m0 + rl) * 1024 + swz; lbase = OFF_ALO; }
    else if (wid == 2) { gsrc = Bhi + (size_t)(hc0 + rl) * 1024 + swz; lbase = OFF_BHI; }
    else               { gsrc = Blo + (size_t)(hc0 + rl) * 1024 + swz; lbase = OFF_BLO; }

    for (int kt = 0; kt < 16; ++kt) {
        if (!first || kt) __syncthreads();
        const f16* g = gsrc + kt * 64;
        if (wid < 2) {
#pragma unroll
            for (int i = 0; i < 16; ++i)
                glds16(g + (size_t)i * 8192, sm + lbase + i * 1024);
        } else {
#pragma unroll
            for (int i = 0; i < 16; ++i) {
                const size_t rowoff =
                    (size_t)(((i >> 1) & 3) * 1024 + (i >> 3) * 16 + (i & 1) * 8) * 1024;
                glds16(g + rowoff, sm + lbase + i * 1024);
            }
        }
        __syncthreads();
        tile_compute(sm, acc, wr0, cs, l15, lk);
    }
}

// Mixed pass: A pairs via glds (waves 0,1); B fp32 [4096][1024] reg-staged +
// split-on-the-fly by all threads (round-2 proven path, same LDS layout).
__device__ __forceinline__ void pass_mixed(
    const f16* __restrict__ Ahi, const f16* __restrict__ Alo,
    const float* __restrict__ Bw,
    int m0, int hc0, f32x4 (&acc)[4][4], char* sm, bool first)
{
    const int tid = threadIdx.x, lane = tid & 63, wid = tid >> 6;
    const int wr0 = (wid >> 1) * 64, cs = wid & 1, l15 = lane & 15, lk = lane >> 4;
    const int rl = lane >> 3, sl = lane & 7;
    const int swz = (sl ^ rl) << 3;
    const f16* gsrc = (wid == 0 ? Ahi : Alo) + (size_t)(m0 + rl) * 1024 + swz;
    const int lbase = (wid == 0) ? OFF_AHI : OFF_ALO;

    const int blv = tid >> 1, bkh = (tid & 1) << 5;
    const int brow = ((blv >> 4) & 3) * 1024 + hc0 + (blv >> 6) * 16 + (blv & 15);
    const float* bsrc = Bw + (size_t)brow * 1024 + bkh;

    float4 bv[8];
    auto loadB = [&](int kt) {
#pragma unroll
        for (int i = 0; i < 8; ++i) bv[i] = *(const float4*)(bsrc + kt * 64 + i * 4);
    };
    auto writeB = [&]() {
#pragma unroll
        for (int i = 0; i < 8; ++i) {
            const float4 v = bv[i];
            const f16 s0 = (f16)v.x, s1 = (f16)v.y, s2 = (f16)v.z, s3 = (f16)v.w;
            const f16x4 hv = {s0, s1, s2, s3};
            const f16x4 lw = {(f16)(v.x - (float)s0), (f16)(v.y - (float)s1),
                              (f16)(v.z - (float)s2), (f16)(v.w - (float)s3)};
            const int kslot = (tid & 1) * 4 + (i >> 1);
            const int off = blv * 128 + ((kslot ^ (blv & 7)) << 4) + (i & 1) * 8;
            *(f16x4*)(sm + OFF_BHI + off) = hv;
            *(f16x4*)(sm + OFF_BLO + off) = lw;
        }
    };

    loadB(0);
    for (int kt = 0; kt < 16; ++kt) {
        if (!first || kt) __syncthreads();
        if (wid < 2) {
            const f16* g = gsrc + kt * 64;
#pragma unroll
            for (int i = 0; i < 16; ++i)
                glds16(g + (size_t)i * 8192, sm + lbase + i * 1024);
        }
        writeB();
        __syncthreads();
        if (kt < 15) loadB(kt + 1);
        tile_compute(sm, acc, wr0, cs, l15, lk);
    }
}

// XCD-major over hc: per-XCD weight slab = 4 hc-tiles x 512KB = 2MB (L2-fit).
__device__ __forceinline__ void block_tile(int& m0, int& hc0) {
    const int bid = blockIdx.x;
    const int lid = (bid & 7) * 128 + (bid >> 3);
    m0  = (lid & 31) * 128;
    hc0 = (lid >> 5) * 32;
}

// Layer-1 cell: gates = x@Wih1'^T (+flag col @step0) + bias + h1@Whh1^T
__global__ __launch_bounds__(256) void k_stepA(
    const f16* __restrict__ xhi, const f16* __restrict__ xlo,
    const f16* __restrict__ W1hi, const f16* __restrict__ W1lo,
    const float* __restrict__ Whh1,
    const f16* __restrict__ h1hi_in, const f16* __restrict__ h1lo_in,
    const float* __restrict__ bih1, const float* __restrict__ bhh1,
    const float* __restrict__ flagcol,
    float* __restrict__ c1,
    f16* __restrict__ h1hi_out, f16* __restrict__ h1lo_out,
    f16* __restrict__ acthi, f16* __restrict__ actlo,
    const unsigned* __restrict__ cnt_prev, int step)
{
    if (step > 0 && cnt_prev[0] == 0u) return;
    __shared__ __align__(16) char sm[65536];
    int m0, hc0; block_tile(m0, hc0);
    f32x4 acc[4][4];
#pragma unroll
    for (int a = 0; a < 4; ++a)
#pragma unroll
        for (int b = 0; b < 4; ++b) acc[a][b] = (f32x4){0.f, 0.f, 0.f, 0.f};

    pass_glds(xhi, xlo, W1hi, W1lo, m0, hc0, acc, sm, true);
    if (step > 0)
        pass_mixed(h1hi_in, h1lo_in, Whh1, m0, hc0, acc, sm, false);

    const int tid = threadIdx.x, lane = tid & 63, wid = tid >> 6;
    const int wr0 = (wid >> 1) * 64, cs = wid & 1, l15 = lane & 15, lk = lane >> 4;
#pragma unroll
    for (int mf = 0; mf < 4; ++mf)
#pragma unroll
        for (int r = 0; r < 4; ++r) {
            const int row = m0 + wr0 + mf * 16 + lk * 4 + r;
            const int hc  = hc0 + cs * 16 + l15;
            float p[4];
#pragma unroll
            for (int g = 0; g < 4; ++g) {
                const int R = g * 1024 + hc;
                p[g] = acc[mf][g][r] + bih1[R] + bhh1[R];
                if (step == 0) p[g] += flagcol[R];
            }
            const float ig = sigmoidf_(p[0]);
            const float fg = sigmoidf_(p[1]);
            const float gg = tanhf(p[2]);
            const float og = sigmoidf_(p[3]);
            const int idx = row * 1024 + hc;
            const float cn = fg * c1[idx] + ig * gg;
            c1[idx] = cn;
            const float h = og * tanhf(cn);
            const f16 hh = (f16)h;
            const f16 hl = (f16)(h - (float)hh);
            h1hi_out[idx] = hh; h1lo_out[idx] = hl;
            const bool pos = h > 0.0f;
            acthi[idx] = pos ? hh : (f16)0.0f;
            actlo[idx] = pos ? hl : (f16)0.0f;
        }
}

// Layer-2 cell: gates = b2 + act@Wih2^T + h2@Whh2^T
__global__ __launch_bounds__(256) void k_stepB(
    const f16* __restrict__ acthi, const f16* __restrict__ actlo,
    const f16* __restrict__ W2hi, const f16* __restrict__ W2lo,
    const f16* __restrict__ h2hi_in, const f16* __restrict__ h2lo_in,
    const f16* __restrict__ W3hi, const f16* __restrict__ W3lo,
    const float* __restrict__ bih2, const float* __restrict__ bhh2,
    float* __restrict__ c2, f16* __restrict__ h2hi_out, f16* __restrict__ h2lo_out,
    const unsigned* __restrict__ cnt_prev, int step)
{
    if (step > 0 && cnt_prev[0] == 0u) return;
    __shared__ __align__(16) char sm[65536];
    int m0, hc0; block_tile(m0, hc0);
    f32x4 acc[4][4];
#pragma unroll
    for (int a = 0; a < 4; ++a)
#pragma unroll
        for (int b = 0; b < 4; ++b) acc[a][b] = (f32x4){0.f, 0.f, 0.f, 0.f};

    pass_glds(acthi, actlo, W2hi, W2lo, m0, hc0, acc, sm, true);
    if (step > 0)
        pass_glds(h2hi_in, h2lo_in, W3hi, W3lo, m0, hc0, acc, sm, false);

    const int tid = threadIdx.x, lane = tid & 63, wid = tid >> 6;
    const int wr0 = (wid >> 1) * 64, cs = wid & 1, l15 = lane & 15, lk = lane >> 4;
#pragma unroll
    for (int mf = 0; mf < 4; ++mf)
#pragma unroll
        for (int r = 0; r < 4; ++r) {
            const int row = m0 + wr0 + mf * 16 + lk * 4 + r;
            const int hc  = hc0 + cs * 16 + l15;
            float p[4];
#pragma unroll
            for (int g = 0; g < 4; ++g) {
                const int R = g * 1024 + hc;
                p[g] = acc[mf][g][r] + bih2[R] + bhh2[R];
            }
            const float ig = sigmoidf_(p[0]);
            const float fg = sigmoidf_(p[1]);
            const float gg = tanhf(p[2]);
            const float og = sigmoidf_(p[3]);
            const int idx = row * 1024 + hc;
            const float cn = fg * c2[idx] + ig * gg;
            c2[idx] = cn;
            const float h = og * tanhf(cn);
            const f16 hh = (f16)h;
            h2hi_out[idx] = hh;
            h2lo_out[idx] = (f16)(h - (float)hh);
        }
}

// Halting state machine (one wave per row)
__global__ __launch_bounds__(256) void k_halt(
    const f16* __restrict__ h2hi, const f16* __restrict__ h2lo,
    const float* __restrict__ Whalt, const float* __restrict__ bhalt,
    float* __restrict__ halt, float* __restrict__ cont, float* __restrict__ coef,
    float* __restrict__ ponder_out, unsigned* __restrict__ ctrl,
    const unsigned* __restrict__ cnt_prev, int step)
{
    if (step > 0 && cnt_prev[0] == 0u) return;
    const int lane = threadIdx.x & 63;
    const int b = blockIdx.x * 4 + (threadIdx.x >> 6);
    const size_t base = (size_t)b * 1024;
    float sum = 0.0f;
    for (int k = lane; k < 1024; k += 64)
        sum += ((float)h2hi[base + k] + (float)h2lo[base + k]) * Whalt[k];
#pragma unroll
    for (int off = 32; off > 0; off >>= 1) sum += __shfl_down(sum, off, 64);
    if (lane == 0) {
        const float sh = sigmoidf_(sum + bhalt[0]);
        float co = 0.0f;
        if (cont[b] != 0.0f) {
            const float hn = halt[b] + sh;
            const bool ending = hn > 0.99f;
            co = sh + (ending ? (1.0f - hn) : 0.0f);
            halt[b] = hn;
            if (!ending) {
                ponder_out[b] += 1.0f;
                atomicAdd(&ctrl[step], 1u);
            } else {
                cont[b] = 0.0f;
            }
        }
        coef[b] = co;
        if (b == 0) ctrl[12] = (unsigned)(step + 1);
    }
}

__global__ __launch_bounds__(256) void k_accum(
    const f16* __restrict__ h2hi, const f16* __restrict__ h2lo,
    const float* __restrict__ coef, float* __restrict__ acc_out,
    const unsigned* __restrict__ cnt_prev, int step)
{
    if (step > 0 && cnt_prev[0] == 0u) return;
    const int b = blockIdx.x;
    const float co = coef[b];
    if (co == 0.0f) return;
    const size_t base = (size_t)b * 1024;
    const int i = threadIdx.x;
    const f16x4 hv = *(const f16x4*)(h2hi + base + i * 4);
    const f16x4 lv = *(const f16x4*)(h2lo + base + i * 4);
    float4* dst = (float4*)(acc_out + base);
    float4 d = dst[i];
    d.x = fmaf(co, (float)hv[0] + (float)lv[0], d.x);
    d.y = fmaf(co, (float)hv[1] + (float)lv[1], d.y);
    d.z = fmaf(co, (float)hv[2] + (float)lv[2], d.z);
    d.w = fmaf(co, (float)hv[3] + (float)lv[3], d.w);
    dst[i] = d;
}

__global__ __launch_bounds__(256) void k_small_init(
    float* __restrict__ halt, float* __restrict__ cont,
    float* __restrict__ ponder_out, unsigned* __restrict__ ctrl)
{
    const int b = blockIdx.x * 256 + threadIdx.x;
    if (b < 4096) { halt[b] = 0.0f; cont[b] = 1.0f; ponder_out[b] = 0.0f; }
    if (b < 16) ctrl[b] = 0u;
}

// flat fp32 -> f16 hi/lo pairs (n = 4096*1024, float4 per thread)
__global__ __launch_bounds__(256) void k_split_flat(
    const float* __restrict__ src, f16* __restrict__ hi, f16* __restrict__ lo)
{
    const size_t i = ((size_t)blockIdx.x * 256 + threadIdx.x) * 4;
    const float4 v = *(const float4*)(src + i);
    const f16 s0 = (f16)v.x, s1 = (f16)v.y, s2 = (f16)v.z, s3 = (f16)v.w;
    const f16x4 hv = {s0, s1, s2, s3};
    const f16x4 lw = {(f16)(v.x - (float)s0), (f16)(v.y - (float)s1),
                      (f16)(v.z - (float)s2), (f16)(v.w - (float)s3)};
    *(f16x4*)(hi + i) = hv;
    *(f16x4*)(lo + i) = lw;
}

// Wih1 [4096][1025]: cols 0..1023 -> pairs; col 1024 -> flagcol
__global__ __launch_bounds__(256) void k_split_wih1(
    const float* __restrict__ src, f16* __restrict__ hi, f16* __restrict__ lo,
    float* __restrict__ flagcol)
{
    const int t = blockIdx.x * 256 + threadIdx.x;   // 1,048,576 threads
    const int row = t >> 8, c4 = (t & 255) << 2;
    const float* s = src + (size_t)row * 1025 + c4;
    const float v0 = s[0], v1 = s[1], v2 = s[2], v3 = s[3];
    const f16 s0 = (f16)v0, s1 = (f16)v1, s2 = (f16)v2, s3 = (f16)v3;
    const f16x4 hv = {s0, s1, s2, s3};
    const f16x4 lw = {(f16)(v0 - (float)s0), (f16)(v1 - (float)s1),
                      (f16)(v2 - (float)s2), (f16)(v3 - (float)s3)};
    const size_t di = (size_t)row * 1024 + c4;
    *(f16x4*)(hi + di) = hv;
    *(f16x4*)(lo + di) = lw;
    if ((t & 255) == 0) flagcol[row] = src[(size_t)row * 1025 + 1024];
}

__global__ __launch_bounds__(256) void k_fin1(
    const f16* __restrict__ h1hi0, const f16* __restrict__ h1hi1,
    const f16* __restrict__ h1lo0, const f16* __restrict__ h1lo1,
    const f16* __restrict__ h2hi0, const f16* __restrict__ h2hi1,
    const f16* __restrict__ h2lo0, const f16* __restrict__ h2lo1,
    const float* __restrict__ c1s, const float* __restrict__ c2s,
    const float* __restrict__ halt, const float* __restrict__ cont,
    const unsigned* __restrict__ ctrl, float* __restrict__ out)
{
    const int par = (int)(ctrl[12] & 1u);
    const f16* h1h = par ? h1hi1 : h1hi0;
    const f16* h1l = par ? h1lo1 : h1lo0;
    const f16* h2h = par ? h2hi1 : h2hi0;
    const f16* h2l = par ? h2lo1 : h2lo0;
    const int b = blockIdx.x;
    const float rem = (cont[b] != 0.0f) ? (1.0f - halt[b]) : 0.0f;
    const int base = b * 1024;
    for (int i = threadIdx.x; i < 1024; i += 256) {
        const float h1v = (float)h1h[base + i] + (float)h1l[base + i];
        const float h2v = (float)h2h[base + i] + (float)h2l[base + i];
        out[O_H1 + base + i] = h1v;
        out[O_C1 + base + i] = c1s[base + i];
        out[O_H2 + base + i] = h2v;
        out[O_C2 + base + i] = c2s[base + i];
        if (rem != 0.0f) out[O_ACC + base + i] += rem * h2v;
    }
}

__global__ __launch_bounds__(256) void k_fin2(
    const float* __restrict__ halt, float* __restrict__ out)
{
    __shared__ float red[256];
    float s = 0.0f;
    for (int i = threadIdx.x; i < 4096; i += 256) s += halt[i];
    red[threadIdx.x] = s;
    __syncthreads();
    for (int w = 128; w > 0; w >>= 1) {
        if (threadIdx.x < w) red[threadIdx.x] += red[threadIdx.x + w];
        __syncthreads();
    }
    if (threadIdx.x == 0) out[O_PCOST] = -0.01f * (red[0] * (1.0f / 4096.0f));
}

extern "C" void kernel_launch(void* const* d_in, const int* in_sizes, int n_in,
                              void* d_out, int out_size, void* d_ws, size_t ws_size,
                              hipStream_t stream) {
    const float* inputs = (const float*)d_in[0];
    const float* W_ih1  = (const float*)d_in[1];
    const float* W_hh1  = (const float*)d_in[2];
    const float* b_ih1  = (const float*)d_in[3];
    const float* b_hh1  = (const float*)d_in[4];
    const float* W_ih2  = (const float*)d_in[5];
    const float* W_hh2  = (const float*)d_in[6];
    const float* b_ih2  = (const float*)d_in[7];
    const float* b_hh2  = (const float*)d_in[8];
    const float* W_halt = (const float*)d_in[9];
    const float* b_halt = (const float*)d_in[10];

    float* out = (float*)d_out;
    char*  ob  = (char*)d_out;
    f16* W1hi = (f16*)(ob + DO_W1HI); f16* W1lo = (f16*)(ob + DO_W1LO);
    f16* W2hi = (f16*)(ob + DO_W2HI); f16* W2lo = (f16*)(ob + DO_W2LO);
    f16* W3hi = (f16*)(ob + DO_W3HI); f16* W3lo = (f16*)(ob + DO_W3LO);
    f16* xhi  = (f16*)(ob + DO_XHI);  f16* xlo  = (f16*)(ob + DO_XLO);

    char* wsb = (char*)d_ws;
    float* c1s = (float*)(wsb + WS_C1);
    float* c2s = (float*)(wsb + WS_C2);
    f16* h1hi[2] = { (f16*)(wsb + WS_H1HI0), (f16*)(wsb + WS_H1HI1) };
    f16* h1lo[2] = { (f16*)(wsb + WS_H1LO0), (f16*)(wsb + WS_H1LO1) };
    f16* h2hi[2] = { (f16*)(wsb + WS_H2HI0), (f16*)(wsb + WS_H2HI1) };
    f16* h2lo[2] = { (f16*)(wsb + WS_H2LO0), (f16*)(wsb + WS_H2LO1) };
    f16* acthi   = (f16*)(wsb + WS_ACTHI);
    f16* actlo   = (f16*)(wsb + WS_ACTLO);
    float* halt    = (float*)(wsb + WS_MISC);
    float* cont    = halt + 4096;
    float* coef    = cont + 4096;
    float* flagcol = coef + 4096;
    unsigned* ctrl = (unsigned*)(flagcol + 4096);

    const size_t mb16 = (size_t)4096 * 1024 * sizeof(float);
    hipMemsetAsync(out + O_ACC, 0, mb16, stream);
    hipMemsetAsync(c1s, 0, mb16, stream);
    hipMemsetAsync(c2s, 0, mb16, stream);
    k_small_init<<<16, 256, 0, stream>>>(halt, cont, out + O_PSTEP, ctrl);

    k_split_wih1<<<4096, 256, 0, stream>>>(W_ih1, W1hi, W1lo, flagcol);
    k_split_flat<<<4096, 256, 0, stream>>>(W_ih2, W2hi, W2lo);
    k_split_flat<<<4096, 256, 0, stream>>>(W_hh2, W3hi, W3lo);
    k_split_flat<<<4096, 256, 0, stream>>>(inputs, xhi, xlo);

    for (int s = 0; s < TSTEPS; ++s) {
        const int wsel = (s & 1) ? 0 : 1;
        const int rsel = 1 - wsel;
        const unsigned* cnt_prev = ctrl + (s > 0 ? s - 1 : 0);

        k_stepA<<<1024, 256, 0, stream>>>(xhi, xlo, W1hi, W1lo, W_hh1,
                                          h1hi[rsel], h1lo[rsel],
                                          b_ih1, b_hh1, flagcol, c1s,
                                          h1hi[wsel], h1lo[wsel], acthi, actlo,
                                          cnt_prev, s);
        k_stepB<<<1024, 256, 0, stream>>>(acthi, actlo, W2hi, W2lo,
                                          h2hi[rsel], h2lo[rsel], W3hi, W3lo,
                                          b_ih2, b_hh2, c2s,
                                          h2hi[wsel], h2lo[wsel],
                                          cnt_prev, s);
        k_halt<<<1024, 256, 0, stream>>>(h2hi[wsel], h2lo[wsel], W_halt, b_halt,
                                         halt, cont, coef, out + O_PSTEP, ctrl,
                                         cnt_prev, s);
        k_accum<<<4096, 256, 0, stream>>>(h2hi[wsel], h2lo[wsel], coef,
                                          out + O_ACC, cnt_prev, s);
    }

    k_fin1<<<4096, 256, 0, stream>>>(h1hi[0], h1hi[1], h1lo[0], h1lo[1],
                                     h2hi[0], h2hi[1], h2lo[0], h2lo[1],
                                     c1s, c2s, halt, cont, ctrl, out);
    k_fin2<<<1, 256, 0, stream>>>(halt, out);
}

// Round 4
// 1482.536 us; speedup vs baseline: 3.7332x; 1.1033x over previous
//
#include <hip/hip_runtime.h>
#include <cstdint>
#include <cstddef>

// ---------------------------------------------------------------------------
// AdaptiveLSTMBlockWrapper — round 4: Z1 restored (kills per-step x@W1 pass)
// + 256x256 8-wave BK=32 double-buffered phased GEMM engine (raw s_barrier,
// counted-issue glds pipeline). fp32 GEMM = 3-product split-f16 MFMA.
//
// - Z1 = x@W1^T + b_ih1 + b_hh1 (fp32, 64MB) in d_out's dead state region.
//   x/W1 f16 pairs staged temporarily in the step-0-dead h ping-pong slots.
// - Per step: stepA = 1 mixed pass (h1 pairs glds-A, Whh1 fp32 reg-split-B)
//   + Z1-add epilogue; stepB = 2 mixed passes (act/W2, h2/W3).
// - Engine: 256 rows x 256 vcols (4 gates x 64 hc), 8 waves (2Mx4N), BK=32,
//   2 LDS buffers x 64KB. Per K-step: 4 phases {ds_read frags | issue glds
//   into next buf | s_barrier | 24 MFMA | s_barrier}; one vmcnt(0)+barrier
//   at the K-step boundary (loads issued phases earlier -> covered).
// - LDS rows 64B, slot^(row&3) XOR swizzle; glds linear dest + inverse-
//   swizzled per-lane global source (both-sides rule).
// ---------------------------------------------------------------------------

typedef _Float16 f16;
typedef f16   f16x8 __attribute__((ext_vector_type(8)));
typedef f16   f16x4 __attribute__((ext_vector_type(4)));
typedef float f32x4 __attribute__((ext_vector_type(4)));

#define TSTEPS 12

// d_out float offsets
#define O_ACC   0u
#define O_H1    4194304u
#define O_C1    8388608u
#define O_H2    12582912u
#define O_C2    16777216u
#define O_PCOST 20971520u
#define O_PSTEP 20971521u

// ws byte offsets
#define WS_C1    (size_t)(0u)
#define WS_C2    ((size_t)16u<<20)
#define WS_H1HI0 ((size_t)32u<<20)
#define WS_H1HI1 ((size_t)40u<<20)
#define WS_H1LO0 ((size_t)48u<<20)
#define WS_H1LO1 ((size_t)56u<<20)
#define WS_H2HI0 ((size_t)64u<<20)
#define WS_H2HI1 ((size_t)72u<<20)
#define WS_H2LO0 ((size_t)80u<<20)
#define WS_H2LO1 ((size_t)88u<<20)
#define WS_ACTHI ((size_t)96u<<20)
#define WS_ACTLO ((size_t)104u<<20)
#define WS_MISC  ((size_t)112u<<20)

// LDS: 2 buffers x 64KB; sections within buffer (bytes)
#define SEC_AHI 0
#define SEC_ALO 16384
#define SEC_BHI 32768
#define SEC_BLO 49152
#define BUFSZ   65536

__device__ __forceinline__ float sigmoidf_(float x) { return 1.0f / (1.0f + expf(-x)); }

__device__ __forceinline__ void glds16(const void* g, void* l) {
    __builtin_amdgcn_global_load_lds(
        (const __attribute__((address_space(1))) unsigned int*)g,
        (__attribute__((address_space(3))) unsigned int*)l, 16, 0, 0);
}

// Grid: 256 blocks (16 m x 16 hc). XCD-major over hc: 2MB weight slab/XCD.
__device__ __forceinline__ void block_tile(int& m0, int& hc0) {
    const int bid = blockIdx.x;
    const int lid = (bid & 7) * 32 + (bid >> 3);
    m0  = (lid & 15) * 256;
    hc0 = (lid >> 4) * 64;
}

// ---------------------------------------------------------------------------
// acc += A(256 rows x 1024) * B(256 vcols x 1024)^T, split-f16 3-product.
// A always pre-split pairs via glds. B: pairs via glds (B_PAIR) or fp32
// reg-staged + split on the fly (!B_PAIR).
// vcol lv decode: g=(lv>>4)&3, hcl=(lv>>6)*16+(lv&15); wrow=g*1024+hc0+hcl.
// Wave wid: rows wm=(wid>>2)*128 (mf 0..7), vcols lv=(wid&3)*64+nf*16+l15
// (g = nf, hc = hc0+(wid&3)*16+l15).
// LDS row = 64B (BK=32 f16), 4 slots of 16B, slot ^= (row&3).
// ---------------------------------------------------------------------------
template<bool B_PAIR>
__device__ __forceinline__ void pass256(
    const f16* __restrict__ Ahi, const f16* __restrict__ Alo,
    const f16* __restrict__ Bhi, const f16* __restrict__ Blo,
    const float* __restrict__ Bf32,
    int m0, int hc0, f32x4 (&acc)[8][4], char* sm)
{
    const int tid = threadIdx.x, lane = tid & 63, wid = tid >> 6;
    const int wm  = (wid >> 2) * 128;
    const int wnb = wid & 3;
    const int l15 = lane & 15, lk = lane >> 4;
    const int rswz16 = (lk ^ (l15 & 3)) << 4;

    // fragment LDS byte offsets (within a buffer)
    int aoff[8], boff[4];
#pragma unroll
    for (int mf = 0; mf < 8; ++mf) aoff[mf] = (wm + mf * 16 + l15) * 64 + rswz16;
#pragma unroll
    for (int nf = 0; nf < 4; ++nf) boff[nf] = (wnb * 64 + nf * 16 + l15) * 64 + rswz16;

    // glds ops: B_PAIR: 8/wave (secs AhiAloBhiBlo); mixed: 4/wave (Ahi,Alo)
    constexpr int NOPS = B_PAIR ? 8 : 4;
    const f16* gsrc[NOPS];
    int ldst[NOPS];
    {
        const int gl_d = lane >> 2;            // row within 16-row chunk
        const int swzel = ((lane & 3) ^ (gl_d & 3)) * 8;   // f16 elems
#pragma unroll
        for (int i = 0; i < NOPS; ++i) {
            const int o = wid * NOPS + i;
            const int sec = o >> 4, j = o & 15;
            const f16* base;
            size_t row;
            if (sec <= 1) { base = (sec == 0) ? Ahi : Alo; row = (size_t)(m0 + 16 * j + gl_d); }
            else {
                base = (sec == 2) ? Bhi : Blo;
                row = (size_t)((j & 3) * 1024 + hc0 + (j >> 2) * 16 + gl_d);
            }
            gsrc[i] = base + row * 1024 + swzel;
            ldst[i] = sec * 16384 + j * 1024 + lane * 16;
        }
    }

    // mixed-B reg staging
    const int blv = tid >> 1;
    const float* bsrc = nullptr;
    float4 breg[4];
    if constexpr (!B_PAIR) {
        const int wrow = ((blv >> 4) & 3) * 1024 + hc0 + (blv >> 6) * 16 + (blv & 15);
        bsrc = Bf32 + (size_t)wrow * 1024 + (tid & 1) * 16;
    }

    auto issue = [&](int i, int kt, char* buf) {
        glds16(gsrc[i] + kt * 32, buf + ldst[i]);
    };
    auto loadB = [&](int kt) {
#pragma unroll
        for (int i = 0; i < 4; ++i) breg[i] = *(const float4*)(bsrc + kt * 32 + i * 4);
    };
    auto writeB = [&](char* buf) {
#pragma unroll
        for (int i = 0; i < 4; ++i) {
            const float4 v = breg[i];
            const f16 s0 = (f16)v.x, s1 = (f16)v.y, s2 = (f16)v.z, s3 = (f16)v.w;
            const f16x4 hv = {s0, s1, s2, s3};
            const f16x4 lw = {(f16)(v.x - (float)s0), (f16)(v.y - (float)s1),
                              (f16)(v.z - (float)s2), (f16)(v.w - (float)s3)};
            const int s = (((tid & 1) * 2 + (i >> 1)) ^ (blv & 3));
            const int off = blv * 64 + (s << 4) + (i & 1) * 8;
            *(f16x4*)(buf + SEC_BHI + off) = hv;
            *(f16x4*)(buf + SEC_BLO + off) = lw;
        }
    };

    // issue spread across phases (front-loaded for latency cover)
    constexpr int IST_P[5] = {0, 3, 6, 8, 8};   // B_PAIR
    constexpr int IST_M[5] = {0, 2, 3, 4, 4};   // mixed

    // ---- prologue: stage K-step 0 into buf0 ----
#pragma unroll
    for (int i = 0; i < NOPS; ++i) issue(i, 0, sm);
    if constexpr (!B_PAIR) {
        loadB(0);
        asm volatile("s_waitcnt vmcnt(0)" ::: "memory");
        writeB(sm);
    }
    asm volatile("s_waitcnt vmcnt(0) lgkmcnt(0)" ::: "memory");
    __builtin_amdgcn_s_barrier();
    asm volatile("" ::: "memory");

    int cur = 0;
#pragma unroll 1
    for (int kt = 0; kt < 32; ++kt) {
        char* bc = sm + cur * BUFSZ;
        char* bn = sm + (cur ^ 1) * BUFSZ;
        const bool pre = (kt < 31);
        f16x8 bh[4], bl[4];
#pragma unroll
        for (int p = 0; p < 4; ++p) {
            // ds_read this phase's A frags (mf = 2p, 2p+1); all B at p==0
            f16x8 ah0 = *(const f16x8*)(bc + SEC_AHI + aoff[2 * p]);
            f16x8 ah1 = *(const f16x8*)(bc + SEC_AHI + aoff[2 * p + 1]);
            f16x8 al0 = *(const f16x8*)(bc + SEC_ALO + aoff[2 * p]);
            f16x8 al1 = *(const f16x8*)(bc + SEC_ALO + aoff[2 * p + 1]);
            if (p == 0) {
#pragma unroll
                for (int nf = 0; nf < 4; ++nf) {
                    bh[nf] = *(const f16x8*)(bc + SEC_BHI + boff[nf]);
                    bl[nf] = *(const f16x8*)(bc + SEC_BLO + boff[nf]);
                }
            }
            if (pre) {
                if constexpr (B_PAIR) {
#pragma unroll
                    for (int i = IST_P[p]; i < IST_P[p + 1]; ++i) issue(i, kt + 1, bn);
                } else {
#pragma unroll
                    for (int i = IST_M[p]; i < IST_M[p + 1]; ++i) issue(i, kt + 1, bn);
                    if (p == 0) loadB(kt + 1);
                }
            }
            __builtin_amdgcn_s_barrier();
#pragma unroll
            for (int i = 0; i < 2; ++i) {
                const f16x8 xh = i ? ah1 : ah0;
                const f16x8 xl = i ? al1 : al0;
#pragma unroll
                for (int nf = 0; nf < 4; ++nf) {
                    acc[2 * p + i][nf] = __builtin_amdgcn_mfma_f32_16x16x32_f16(xh, bh[nf], acc[2 * p + i][nf], 0, 0, 0);
                    acc[2 * p + i][nf] = __builtin_amdgcn_mfma_f32_16x16x32_f16(xh, bl[nf], acc[2 * p + i][nf], 0, 0, 0);
                    acc[2 * p + i][nf] = __builtin_amdgcn_mfma_f32_16x16x32_f16(xl, bh[nf], acc[2 * p + i][nf], 0, 0, 0);
                }
            }
            if (p < 3) __builtin_amdgcn_s_barrier();
        }
        // K-step boundary: my next-buf writes landed, then block-wide sync
        asm volatile("s_waitcnt vmcnt(0)" ::: "memory");
        if constexpr (!B_PAIR) { if (pre) writeB(bn); }
        asm volatile("s_waitcnt lgkmcnt(0)" ::: "memory");
        __builtin_amdgcn_s_barrier();
        asm volatile("" ::: "memory");
        cur ^= 1;
    }
}

// Z1 = x@W1^T + b_ih1 + b_hh1 (all operands pre-split pairs)
__global__ __launch_bounds__(512) void k_z1(
    const f16* __restrict__ xhi, const f16* __restrict__ xlo,
    const f16* __restrict__ W1hi, const f16* __restrict__ W1lo,
    const float* __restrict__ bih1, const float* __restrict__ bhh1,
    float* __restrict__ Z1)
{
    __shared__ __align__(16) char sm[2 * BUFSZ];
    int m0, hc0; block_tile(m0, hc0);
    f32x4 acc[8][4];
#pragma unroll
    for (int a = 0; a < 8; ++a)
#pragma unroll
        for (int b = 0; b < 4; ++b) acc[a][b] = (f32x4){0.f, 0.f, 0.f, 0.f};
    pass256<true>(xhi, xlo, W1hi, W1lo, nullptr, m0, hc0, acc, sm);

    const int tid = threadIdx.x, lane = tid & 63, wid = tid >> 6;
    const int wm = (wid >> 2) * 128, wnb = wid & 3, l15 = lane & 15, lk = lane >> 4;
    const int hc = hc0 + wnb * 16 + l15;
#pragma unroll
    for (int mf = 0; mf < 8; ++mf)
#pragma unroll
        for (int r = 0; r < 4; ++r) {
            const int row = m0 + wm + mf * 16 + lk * 4 + r;
#pragma unroll
            for (int g = 0; g < 4; ++g) {
                const int R = g * 1024 + hc;
                Z1[(size_t)row * 4096 + R] = acc[mf][g][r] + bih1[R] + bhh1[R];
            }
        }
}

// Layer-1 cell: gates = Z1 (+flag col @step0) + h1@Whh1^T
__global__ __launch_bounds__(512) void k_stepA(
    const float* __restrict__ Z1, const float* __restrict__ Whh1,
    const f16* __restrict__ h1hi_in, const f16* __restrict__ h1lo_in,
    const float* __restrict__ flagcol, float* __restrict__ c1,
    f16* __restrict__ h1hi_out, f16* __restrict__ h1lo_out,
    f16* __restrict__ acthi, f16* __restrict__ actlo,
    const unsigned* __restrict__ cnt_prev, int step)
{
    if (step > 0 && cnt_prev[0] == 0u) return;
    __shared__ __align__(16) char sm[2 * BUFSZ];
    int m0, hc0; block_tile(m0, hc0);
    f32x4 acc[8][4];
#pragma unroll
    for (int a = 0; a < 8; ++a)
#pragma unroll
        for (int b = 0; b < 4; ++b) acc[a][b] = (f32x4){0.f, 0.f, 0.f, 0.f};
    if (step > 0)
        pass256<false>(h1hi_in, h1lo_in, nullptr, nullptr, Whh1, m0, hc0, acc, sm);

    const int tid = threadIdx.x, lane = tid & 63, wid = tid >> 6;
    const int wm = (wid >> 2) * 128, wnb = wid & 3, l15 = lane & 15, lk = lane >> 4;
    const int hc = hc0 + wnb * 16 + l15;
#pragma unroll
    for (int mf = 0; mf < 8; ++mf)
#pragma unroll
        for (int r = 0; r < 4; ++r) {
            const int row = m0 + wm + mf * 16 + lk * 4 + r;
            float p[4];
#pragma unroll
            for (int g = 0; g < 4; ++g) {
                const int R = g * 1024 + hc;
                p[g] = acc[mf][g][r] + Z1[(size_t)row * 4096 + R];
                if (step == 0) p[g] += flagcol[R];
            }
            const float ig = sigmoidf_(p[0]);
            const float fg = sigmoidf_(p[1]);
            const float gg = tanhf(p[2]);
            const float og = sigmoidf_(p[3]);
            const int idx = row * 1024 + hc;
            const float cn = fg * c1[idx] + ig * gg;
            c1[idx] = cn;
            const float h = og * tanhf(cn);
            const f16 hh = (f16)h;
            const f16 hl = (f16)(h - (float)hh);
            h1hi_out[idx] = hh; h1lo_out[idx] = hl;
            const bool pos = h > 0.0f;
            acthi[idx] = pos ? hh : (f16)0.0f;
            actlo[idx] = pos ? hl : (f16)0.0f;
        }
}

// Layer-2 cell: gates = b2 + act@Wih2^T + h2@Whh2^T
__global__ __launch_bounds__(512) void k_stepB(
    const f16* __restrict__ acthi, const f16* __restrict__ actlo,
    const float* __restrict__ Wih2,
    const f16* __restrict__ h2hi_in, const f16* __restrict__ h2lo_in,
    const float* __restrict__ Whh2,
    const float* __restrict__ bih2, const float* __restrict__ bhh2,
    float* __restrict__ c2, f16* __restrict__ h2hi_out, f16* __restrict__ h2lo_out,
    const unsigned* __restrict__ cnt_prev, int step)
{
    if (step > 0 && cnt_prev[0] == 0u) return;
    __shared__ __align__(16) char sm[2 * BUFSZ];
    int m0, hc0; block_tile(m0, hc0);
    f32x4 acc[8][4];
#pragma unroll
    for (int a = 0; a < 8; ++a)
#pragma unroll
        for (int b = 0; b < 4; ++b) acc[a][b] = (f32x4){0.f, 0.f, 0.f, 0.f};
    pass256<false>(acthi, actlo, nullptr, nullptr, Wih2, m0, hc0, acc, sm);
    if (step > 0)
        pass256<false>(h2hi_in, h2lo_in, nullptr, nullptr, Whh2, m0, hc0, acc, sm);

    const int tid = threadIdx.x, lane = tid & 63, wid = tid >> 6;
    const int wm = (wid >> 2) * 128, wnb = wid & 3, l15 = lane & 15, lk = lane >> 4;
    const int hc = hc0 + wnb * 16 + l15;
#pragma unroll
    for (int mf = 0; mf < 8; ++mf)
#pragma unroll
        for (int r = 0; r < 4; ++r) {
            const int row = m0 + wm + mf * 16 + lk * 4 + r;
            float p[4];
#pragma unroll
            for (int g = 0; g < 4; ++g) {
                const int R = g * 1024 + hc;
                p[g] = acc[mf][g][r] + bih2[R] + bhh2[R];
            }
            const float ig = sigmoidf_(p[0]);
            const float fg = sigmoidf_(p[1]);
            const float gg = tanhf(p[2]);
            const float og = sigmoidf_(p[3]);
            const int idx = row * 1024 + hc;
            const float cn = fg * c2[idx] + ig * gg;
            c2[idx] = cn;
            const float h = og * tanhf(cn);
            const f16 hh = (f16)h;
            h2hi_out[idx] = hh;
            h2lo_out[idx] = (f16)(h - (float)hh);
        }
}

// Halting state machine (one wave per row)
__global__ __launch_bounds__(256) void k_halt(
    const f16* __restrict__ h2hi, const f16* __restrict__ h2lo,
    const float* __restrict__ Whalt, const float* __restrict__ bhalt,
    float* __restrict__ halt, float* __restrict__ cont, float* __restrict__ coef,
    float* __restrict__ ponder_out, unsigned* __restrict__ ctrl,
    const unsigned* __restrict__ cnt_prev, int step)
{
    if (step > 0 && cnt_prev[0] == 0u) return;
    const int lane = threadIdx.x & 63;
    const int b = blockIdx.x * 4 + (threadIdx.x >> 6);
    const size_t base = (size_t)b * 1024;
    float sum = 0.0f;
    for (int k = lane; k < 1024; k += 64)
        sum += ((float)h2hi[base + k] + (float)h2lo[base + k]) * Whalt[k];
#pragma unroll
    for (int off = 32; off > 0; off >>= 1) sum += __shfl_down(sum, off, 64);
    if (lane == 0) {
        const float sh = sigmoidf_(sum + bhalt[0]);
        float co = 0.0f;
        if (cont[b] != 0.0f) {
            const float hn = halt[b] + sh;
            const bool ending = hn > 0.99f;
            co = sh + (ending ? (1.0f - hn) : 0.0f);
            halt[b] = hn;
            if (!ending) {
                ponder_out[b] += 1.0f;
                atomicAdd(&ctrl[step], 1u);
            } else {
                cont[b] = 0.0f;
            }
        }
        coef[b] = co;
        if (b == 0) ctrl[12] = (unsigned)(step + 1);
    }
}

__global__ __launch_bounds__(256) void k_accum(
    const f16* __restrict__ h2hi, const f16* __restrict__ h2lo,
    const float* __restrict__ coef, float* __restrict__ acc_out,
    const unsigned* __restrict__ cnt_prev, int step)
{
    if (step > 0 && cnt_prev[0] == 0u) return;
    const int b = blockIdx.x;
    const float co = coef[b];
    if (co == 0.0f) return;
    const size_t base = (size_t)b * 1024;
    const int i = threadIdx.x;
    const f16x4 hv = *(const f16x4*)(h2hi + base + i * 4);
    const f16x4 lv = *(const f16x4*)(h2lo + base + i * 4);
    float4* dst = (float4*)(acc_out + base);
    float4 d = dst[i];
    d.x = fmaf(co, (float)hv[0] + (float)lv[0], d.x);
    d.y = fmaf(co, (float)hv[1] + (float)lv[1], d.y);
    d.z = fmaf(co, (float)hv[2] + (float)lv[2], d.z);
    d.w = fmaf(co, (float)hv[3] + (float)lv[3], d.w);
    dst[i] = d;
}

__global__ __launch_bounds__(256) void k_small_init(
    float* __restrict__ halt, float* __restrict__ cont,
    float* __restrict__ ponder_out, unsigned* __restrict__ ctrl)
{
    const int b = blockIdx.x * 256 + threadIdx.x;
    if (b < 4096) { halt[b] = 0.0f; cont[b] = 1.0f; ponder_out[b] = 0.0f; }
    if (b < 16) ctrl[b] = 0u;
}

// flat fp32 -> f16 hi/lo pairs (4096*1024 elements)
__global__ __launch_bounds__(256) void k_split_flat(
    const float* __restrict__ src, f16* __restrict__ hi, f16* __restrict__ lo)
{
    const size_t i = ((size_t)blockIdx.x * 256 + threadIdx.x) * 4;
    const float4 v = *(const float4*)(src + i);
    const f16 s0 = (f16)v.x, s1 = (f16)v.y, s2 = (f16)v.z, s3 = (f16)v.w;
    const f16x4 hv = {s0, s1, s2, s3};
    const f16x4 lw = {(f16)(v.x - (float)s0), (f16)(v.y - (float)s1),
                      (f16)(v.z - (float)s2), (f16)(v.w - (float)s3)};
    *(f16x4*)(hi + i) = hv;
    *(f16x4*)(lo + i) = lw;
}

// Wih1 [4096][1025]: cols 0..1023 -> pairs; col 1024 -> flagcol
__global__ __launch_bounds__(256) void k_split_wih1(
    const float* __restrict__ src, f16* __restrict__ hi, f16* __restrict__ lo,
    float* __restrict__ flagcol)
{
    const int t = blockIdx.x * 256 + threadIdx.x;
    const int row = t >> 8, c4 = (t & 255) << 2;
    const float* s = src + (size_t)row * 1025 + c4;
    const float v0 = s[0], v1 = s[1], v2 = s[2], v3 = s[3];
    const f16 s0 = (f16)v0, s1 = (f16)v1, s2 = (f16)v2, s3 = (f16)v3;
    const f16x4 hv = {s0, s1, s2, s3};
    const f16x4 lw = {(f16)(v0 - (float)s0), (f16)(v1 - (float)s1),
                      (f16)(v2 - (float)s2), (f16)(v3 - (float)s3)};
    const size_t di = (size_t)row * 1024 + c4;
    *(f16x4*)(hi + di) = hv;
    *(f16x4*)(lo + di) = lw;
    if ((t & 255) == 0) flagcol[row] = src[(size_t)row * 1025 + 1024];
}

__global__ __launch_bounds__(256) void k_fin1(
    const f16* __restrict__ h1hi0, const f16* __restrict__ h1hi1,
    const f16* __restrict__ h1lo0, const f16* __restrict__ h1lo1,
    const f16* __restrict__ h2hi0, const f16* __restrict__ h2hi1,
    const f16* __restrict__ h2lo0, const f16* __restrict__ h2lo1,
    const float* __restrict__ c1s, const float* __restrict__ c2s,
    const float* __restrict__ halt, const float* __restrict__ cont,
    const unsigned* __restrict__ ctrl, float* __restrict__ out)
{
    const int par = (int)(ctrl[12] & 1u);
    const f16* h1h = par ? h1hi1 : h1hi0;
    const f16* h1l = par ? h1lo1 : h1lo0;
    const f16* h2h = par ? h2hi1 : h2hi0;
    const f16* h2l = par ? h2lo1 : h2lo0;
    const int b = blockIdx.x;
    const float rem = (cont[b] != 0.0f) ? (1.0f - halt[b]) : 0.0f;
    const int base = b * 1024;
    for (int i = threadIdx.x; i < 1024; i += 256) {
        const float h1v = (float)h1h[base + i] + (float)h1l[base + i];
        const float h2v = (float)h2h[base + i] + (float)h2l[base + i];
        out[O_H1 + base + i] = h1v;
        out[O_C1 + base + i] = c1s[base + i];
        out[O_H2 + base + i] = h2v;
        out[O_C2 + base + i] = c2s[base + i];
        if (rem != 0.0f) out[O_ACC + base + i] += rem * h2v;
    }
}

__global__ __launch_bounds__(256) void k_fin2(
    const float* __restrict__ halt, float* __restrict__ out)
{
    __shared__ float red[256];
    float s = 0.0f;
    for (int i = threadIdx.x; i < 4096; i += 256) s += halt[i];
    red[threadIdx.x] = s;
    __syncthreads();
    for (int w = 128; w > 0; w >>= 1) {
        if (threadIdx.x < w) red[threadIdx.x] += red[threadIdx.x + w];
        __syncthreads();
    }
    if (threadIdx.x == 0) out[O_PCOST] = -0.01f * (red[0] * (1.0f / 4096.0f));
}

extern "C" void kernel_launch(void* const* d_in, const int* in_sizes, int n_in,
                              void* d_out, int out_size, void* d_ws, size_t ws_size,
                              hipStream_t stream) {
    const float* inputs = (const float*)d_in[0];
    const float* W_ih1  = (const float*)d_in[1];
    const float* W_hh1  = (const float*)d_in[2];
    const float* b_ih1  = (const float*)d_in[3];
    const float* b_hh1  = (const float*)d_in[4];
    const float* W_ih2  = (const float*)d_in[5];
    const float* W_hh2  = (const float*)d_in[6];
    const float* b_ih2  = (const float*)d_in[7];
    const float* b_hh2  = (const float*)d_in[8];
    const float* W_halt = (const float*)d_in[9];
    const float* b_halt = (const float*)d_in[10];

    float* out = (float*)d_out;
    float* Z1  = out + O_H1;                  // 64 MB in d_out's dead state region

    char* wsb = (char*)d_ws;
    float* c1s = (float*)(wsb + WS_C1);
    float* c2s = (float*)(wsb + WS_C2);
    f16* h1hi[2] = { (f16*)(wsb + WS_H1HI0), (f16*)(wsb + WS_H1HI1) };
    f16* h1lo[2] = { (f16*)(wsb + WS_H1LO0), (f16*)(wsb + WS_H1LO1) };
    f16* h2hi[2] = { (f16*)(wsb + WS_H2HI0), (f16*)(wsb + WS_H2HI1) };
    f16* h2lo[2] = { (f16*)(wsb + WS_H2LO0), (f16*)(wsb + WS_H2LO1) };
    f16* acthi   = (f16*)(wsb + WS_ACTHI);
    f16* actlo   = (f16*)(wsb + WS_ACTLO);
    float* halt    = (float*)(wsb + WS_MISC);
    float* cont    = halt + 4096;
    float* coef    = cont + 4096;
    float* flagcol = coef + 4096;
    unsigned* ctrl = (unsigned*)(flagcol + 4096);

    // x / W1 pairs live in the step-0-dead h ping-pong set 0 slots
    f16* xhi  = h1hi[0]; f16* xlo  = h1lo[0];
    f16* W1hi = h2hi[0]; f16* W1lo = h2lo[0];

    const size_t mb16 = (size_t)4096 * 1024 * sizeof(float);
    hipMemsetAsync(out + O_ACC, 0, mb16, stream);
    hipMemsetAsync(c1s, 0, mb16, stream);
    hipMemsetAsync(c2s, 0, mb16, stream);
    k_small_init<<<16, 256, 0, stream>>>(halt, cont, out + O_PSTEP, ctrl);

    k_split_wih1<<<4096, 256, 0, stream>>>(W_ih1, W1hi, W1lo, flagcol);
    k_split_flat<<<4096, 256, 0, stream>>>(inputs, xhi, xlo);
    k_z1<<<256, 512, 0, stream>>>(xhi, xlo, W1hi, W1lo, b_ih1, b_hh1, Z1);

    for (int s = 0; s < TSTEPS; ++s) {
        const int wsel = (s & 1) ? 0 : 1;
        const int rsel = 1 - wsel;
        const unsigned* cnt_prev = ctrl + (s > 0 ? s - 1 : 0);

        k_stepA<<<256, 512, 0, stream>>>(Z1, W_hh1, h1hi[rsel], h1lo[rsel],
                                         flagcol, c1s,
                                         h1hi[wsel], h1lo[wsel], acthi, actlo,
                                         cnt_prev, s);
        k_stepB<<<256, 512, 0, stream>>>(acthi, actlo, W_ih2,
                                         h2hi[rsel], h2lo[rsel], W_hh2,
                                         b_ih2, b_hh2, c2s,
                                         h2hi[wsel], h2lo[wsel],
                                         cnt_prev, s);
        k_halt<<<1024, 256, 0, stream>>>(h2hi[wsel], h2lo[wsel], W_halt, b_halt,
                                         halt, cont, coef, out + O_PSTEP, ctrl,
                                         cnt_prev, s);
        k_accum<<<4096, 256, 0, stream>>>(h2hi[wsel], h2lo[wsel], coef,
                                          out + O_ACC, cnt_prev, s);
    }

    k_fin1<<<4096, 256, 0, stream>>>(h1hi[0], h1hi[1], h1lo[0], h1lo[1],
                                     h2hi[0], h2hi[1], h2lo[0], h2lo[1],
                                     c1s, c2s, halt, cont, ctrl, out);
    k_fin2<<<1, 256, 0, stream>>>(halt, out);
}

// Round 5
// 1476.013 us; speedup vs baseline: 3.7497x; 1.0044x over previous
//
#include <hip/hip_runtime.h>
#include <cstdint>
#include <cstddef>

// ---------------------------------------------------------------------------
// AdaptiveLSTMBlockWrapper — round 5: bank-conflict-free LDS (swz4 swizzle +
// 16B B-writes), setprio around MFMA, merged halt+accum, no big memsets.
// Engine: 256x256 8-wave BK=32 double-buffered phased GEMM (round-4 schedule).
// fp32 GEMM = 3-product split-f16 MFMA (Ah*Bh + Ah*Bl + Al*Bh).
//
// LDS invariant: buf[r][slot] holds k-chunk (slot ^ swz4(r)) of logical row r,
// swz4(r) = ((r>>1)^(r>>3))&3. Applied on glds SOURCE (pre-swizzle), on the
// mixed-B ds_write slot, and on every fragment ds_read (both-sides rule).
// ---------------------------------------------------------------------------

typedef _Float16 f16;
typedef f16   f16x8 __attribute__((ext_vector_type(8)));
typedef f16   f16x4 __attribute__((ext_vector_type(4)));
typedef float f32x4 __attribute__((ext_vector_type(4)));

#define TSTEPS 12

// d_out float offsets
#define O_ACC   0u
#define O_H1    4194304u
#define O_C1    8388608u
#define O_H2    12582912u
#define O_C2    16777216u
#define O_PCOST 20971520u
#define O_PSTEP 20971521u

// ws byte offsets
#define WS_C1    (size_t)(0u)
#define WS_C2    ((size_t)16u<<20)
#define WS_H1HI0 ((size_t)32u<<20)
#define WS_H1HI1 ((size_t)40u<<20)
#define WS_H1LO0 ((size_t)48u<<20)
#define WS_H1LO1 ((size_t)56u<<20)
#define WS_H2HI0 ((size_t)64u<<20)
#define WS_H2HI1 ((size_t)72u<<20)
#define WS_H2LO0 ((size_t)80u<<20)
#define WS_H2LO1 ((size_t)88u<<20)
#define WS_ACTHI ((size_t)96u<<20)
#define WS_ACTLO ((size_t)104u<<20)
#define WS_MISC  ((size_t)112u<<20)

// LDS: 2 buffers x 64KB; sections within buffer (bytes)
#define SEC_AHI 0
#define SEC_ALO 16384
#define SEC_BHI 32768
#define SEC_BLO 49152
#define BUFSZ   65536

__device__ __forceinline__ float sigmoidf_(float x) { return 1.0f / (1.0f + expf(-x)); }

__device__ __forceinline__ void glds16(const void* g, void* l) {
    __builtin_amdgcn_global_load_lds(
        (const __attribute__((address_space(1))) unsigned int*)g,
        (__attribute__((address_space(3))) unsigned int*)l, 16, 0, 0);
}

// Grid: 256 blocks (16 m x 16 hc). XCD-major over hc: 2MB weight slab/XCD.
__device__ __forceinline__ void block_tile(int& m0, int& hc0) {
    const int bid = blockIdx.x;
    const int lid = (bid & 7) * 32 + (bid >> 3);
    m0  = (lid & 15) * 256;
    hc0 = (lid >> 4) * 64;
}

// ---------------------------------------------------------------------------
// acc += A(256 rows x 1024) * B(256 vcols x 1024)^T, split-f16 3-product.
// A always pre-split pairs via glds. B: pairs via glds (B_PAIR) or fp32
// reg-staged + split on the fly (!B_PAIR).
// vcol lv decode: g=(lv>>4)&3, hcl=(lv>>6)*16+(lv&15); wrow=g*1024+hc0+hcl.
// Wave wid: rows wm=(wid>>2)*128 (mf 0..7), vcols lv=(wid&3)*64+nf*16+l15.
// LDS row = 64B (BK=32 f16), 4 slots of 16B, slot ^= swz4(row).
// ---------------------------------------------------------------------------
template<bool B_PAIR>
__device__ __forceinline__ void pass256(
    const f16* __restrict__ Ahi, const f16* __restrict__ Alo,
    const f16* __restrict__ Bhi, const f16* __restrict__ Blo,
    const float* __restrict__ Bf32,
    int m0, int hc0, f32x4 (&acc)[8][4], char* sm)
{
    const int tid = threadIdx.x, lane = tid & 63, wid = tid >> 6;
    const int wm  = (wid >> 2) * 128;
    const int wnb = wid & 3;
    const int l15 = lane & 15, lk = lane >> 4;

    // fragment LDS byte offsets (within a buffer), swz4-swizzled
    int aoff[8], boff[4];
#pragma unroll
    for (int mf = 0; mf < 8; ++mf) {
        const int row = wm + mf * 16 + l15;
        aoff[mf] = row * 64 + ((lk ^ (((row >> 1) ^ (row >> 3)) & 3)) << 4);
    }
#pragma unroll
    for (int nf = 0; nf < 4; ++nf) {
        const int lv = wnb * 64 + nf * 16 + l15;
        boff[nf] = lv * 64 + ((lk ^ (((lv >> 1) ^ (lv >> 3)) & 3)) << 4);
    }

    // glds ops: B_PAIR: 8/wave (AhiAloBhiBlo); mixed: 4/wave (Ahi,Alo)
    constexpr int NOPS = B_PAIR ? 8 : 4;
    const f16* gsrc[NOPS];
    int ldst[NOPS];
    {
        const int gl_d = lane >> 2;          // row within 16-row chunk
        const int sl   = lane & 3;           // physical slot this lane fills
        const int swz_gd = ((gl_d >> 1) ^ (gl_d >> 3)) & 3;
#pragma unroll
        for (int i = 0; i < NOPS; ++i) {
            const int o = wid * NOPS + i;
            const int sec = o >> 4, j = o & 15;
            const int swzv = (swz_gd ^ (2 * j)) & 3;   // swz4(ldsrow = j*16+gl_d)
            const f16* base;
            size_t row;
            if (sec <= 1) { base = (sec == 0) ? Ahi : Alo; row = (size_t)(m0 + 16 * j + gl_d); }
            else {
                base = (sec == 2) ? Bhi : Blo;
                row = (size_t)((j & 3) * 1024 + hc0 + (j >> 2) * 16 + gl_d);
            }
            gsrc[i] = base + row * 1024 + ((sl ^ swzv) << 3);
            ldst[i] = sec * 16384 + j * 1024 + lane * 16;
        }
    }

    // mixed-B reg staging
    const int blv = tid >> 1;
    const int bswz = ((blv >> 1) ^ (blv >> 3)) & 3;
    const float* bsrc = nullptr;
    float4 breg[4];
    if constexpr (!B_PAIR) {
        const int wrow = ((blv >> 4) & 3) * 1024 + hc0 + (blv >> 6) * 16 + (blv & 15);
        bsrc = Bf32 + (size_t)wrow * 1024 + (tid & 1) * 16;
    }

    auto issue = [&](int i, int kt, char* buf) {
        glds16(gsrc[i] + kt * 32, buf + ldst[i]);
    };
    auto loadB = [&](int kt) {
#pragma unroll
        for (int i = 0; i < 4; ++i) breg[i] = *(const float4*)(bsrc + kt * 32 + i * 4);
    };
    // split + write as two 16B chunks per section (conflict-free with swz4)
    auto writeB = [&](char* buf) {
#pragma unroll
        for (int i2 = 0; i2 < 2; ++i2) {
            const float4 va = breg[2 * i2], vb = breg[2 * i2 + 1];
            const f16 h0 = (f16)va.x, h1 = (f16)va.y, h2 = (f16)va.z, h3 = (f16)va.w;
            const f16 h4 = (f16)vb.x, h5 = (f16)vb.y, h6 = (f16)vb.z, h7 = (f16)vb.w;
            const f16x8 hv = {h0, h1, h2, h3, h4, h5, h6, h7};
            const f16x8 lw = {(f16)(va.x - (float)h0), (f16)(va.y - (float)h1),
                              (f16)(va.z - (float)h2), (f16)(va.w - (float)h3),
                              (f16)(vb.x - (float)h4), (f16)(vb.y - (float)h5),
                              (f16)(vb.z - (float)h6), (f16)(vb.w - (float)h7)};
            const int slot = ((tid & 1) * 2 + i2) ^ bswz;
            const int off = blv * 64 + (slot << 4);
            *(f16x8*)(buf + SEC_BHI + off) = hv;
            *(f16x8*)(buf + SEC_BLO + off) = lw;
        }
    };

    // issue spread across phases (front-loaded for latency cover)
    constexpr int IST_P[5] = {0, 3, 6, 8, 8};   // B_PAIR
    constexpr int IST_M[5] = {0, 2, 3, 4, 4};   // mixed

    // ---- prologue: stage K-step 0 into buf0 ----
#pragma unroll
    for (int i = 0; i < NOPS; ++i) issue(i, 0, sm);
    if constexpr (!B_PAIR) {
        loadB(0);
        asm volatile("s_waitcnt vmcnt(0)" ::: "memory");
        writeB(sm);
    }
    asm volatile("s_waitcnt vmcnt(0) lgkmcnt(0)" ::: "memory");
    __builtin_amdgcn_s_barrier();
    asm volatile("" ::: "memory");

    int cur = 0;
#pragma unroll 1
    for (int kt = 0; kt < 32; ++kt) {
        char* bc = sm + cur * BUFSZ;
        char* bn = sm + (cur ^ 1) * BUFSZ;
        const bool pre = (kt < 31);
        f16x8 bh[4], bl[4];
#pragma unroll
        for (int p = 0; p < 4; ++p) {
            // ds_read this phase's A frags (mf = 2p, 2p+1); all B at p==0
            f16x8 ah0 = *(const f16x8*)(bc + SEC_AHI + aoff[2 * p]);
            f16x8 ah1 = *(const f16x8*)(bc + SEC_AHI + aoff[2 * p + 1]);
            f16x8 al0 = *(const f16x8*)(bc + SEC_ALO + aoff[2 * p]);
            f16x8 al1 = *(const f16x8*)(bc + SEC_ALO + aoff[2 * p + 1]);
            if (p == 0) {
#pragma unroll
                for (int nf = 0; nf < 4; ++nf) {
                    bh[nf] = *(const f16x8*)(bc + SEC_BHI + boff[nf]);
                    bl[nf] = *(const f16x8*)(bc + SEC_BLO + boff[nf]);
                }
            }
            if (pre) {
                if constexpr (B_PAIR) {
#pragma unroll
                    for (int i = IST_P[p]; i < IST_P[p + 1]; ++i) issue(i, kt + 1, bn);
                } else {
#pragma unroll
                    for (int i = IST_M[p]; i < IST_M[p + 1]; ++i) issue(i, kt + 1, bn);
                    if (p == 0) loadB(kt + 1);
                }
            }
            __builtin_amdgcn_s_barrier();
            __builtin_amdgcn_s_setprio(1);
#pragma unroll
            for (int i = 0; i < 2; ++i) {
                const f16x8 xh = i ? ah1 : ah0;
                const f16x8 xl = i ? al1 : al0;
#pragma unroll
                for (int nf = 0; nf < 4; ++nf) {
                    acc[2 * p + i][nf] = __builtin_amdgcn_mfma_f32_16x16x32_f16(xh, bh[nf], acc[2 * p + i][nf], 0, 0, 0);
                    acc[2 * p + i][nf] = __builtin_amdgcn_mfma_f32_16x16x32_f16(xh, bl[nf], acc[2 * p + i][nf], 0, 0, 0);
                    acc[2 * p + i][nf] = __builtin_amdgcn_mfma_f32_16x16x32_f16(xl, bh[nf], acc[2 * p + i][nf], 0, 0, 0);
                }
            }
            __builtin_amdgcn_s_setprio(0);
            if (p < 3) __builtin_amdgcn_s_barrier();
        }
        // K-step boundary: my next-buf loads landed, then block-wide sync
        asm volatile("s_waitcnt vmcnt(0)" ::: "memory");
        if constexpr (!B_PAIR) { if (pre) writeB(bn); }
        asm volatile("s_waitcnt lgkmcnt(0)" ::: "memory");
        __builtin_amdgcn_s_barrier();
        asm volatile("" ::: "memory");
        cur ^= 1;
    }
}

// Z1 = x@W1^T + b_ih1 + b_hh1 (all operands pre-split pairs)
__global__ __launch_bounds__(512) void k_z1(
    const f16* __restrict__ xhi, const f16* __restrict__ xlo,
    const f16* __restrict__ W1hi, const f16* __restrict__ W1lo,
    const float* __restrict__ bih1, const float* __restrict__ bhh1,
    float* __restrict__ Z1)
{
    __shared__ __align__(16) char sm[2 * BUFSZ];
    int m0, hc0; block_tile(m0, hc0);
    f32x4 acc[8][4];
#pragma unroll
    for (int a = 0; a < 8; ++a)
#pragma unroll
        for (int b = 0; b < 4; ++b) acc[a][b] = (f32x4){0.f, 0.f, 0.f, 0.f};
    pass256<true>(xhi, xlo, W1hi, W1lo, nullptr, m0, hc0, acc, sm);

    const int tid = threadIdx.x, lane = tid & 63, wid = tid >> 6;
    const int wm = (wid >> 2) * 128, wnb = wid & 3, l15 = lane & 15, lk = lane >> 4;
    const int hc = hc0 + wnb * 16 + l15;
#pragma unroll
    for (int mf = 0; mf < 8; ++mf)
#pragma unroll
        for (int r = 0; r < 4; ++r) {
            const int row = m0 + wm + mf * 16 + lk * 4 + r;
#pragma unroll
            for (int g = 0; g < 4; ++g) {
                const int R = g * 1024 + hc;
                Z1[(size_t)row * 4096 + R] = acc[mf][g][r] + bih1[R] + bhh1[R];
            }
        }
}

// Layer-1 cell: gates = Z1 (+flag col @step0) + h1@Whh1^T
__global__ __launch_bounds__(512) void k_stepA(
    const float* __restrict__ Z1, const float* __restrict__ Whh1,
    const f16* __restrict__ h1hi_in, const f16* __restrict__ h1lo_in,
    const float* __restrict__ flagcol, float* __restrict__ c1,
    f16* __restrict__ h1hi_out, f16* __restrict__ h1lo_out,
    f16* __restrict__ acthi, f16* __restrict__ actlo,
    const unsigned* __restrict__ cnt_prev, int step)
{
    if (step > 0 && cnt_prev[0] == 0u) return;
    __shared__ __align__(16) char sm[2 * BUFSZ];
    int m0, hc0; block_tile(m0, hc0);
    f32x4 acc[8][4];
#pragma unroll
    for (int a = 0; a < 8; ++a)
#pragma unroll
        for (int b = 0; b < 4; ++b) acc[a][b] = (f32x4){0.f, 0.f, 0.f, 0.f};
    if (step > 0)
        pass256<false>(h1hi_in, h1lo_in, nullptr, nullptr, Whh1, m0, hc0, acc, sm);

    const int tid = threadIdx.x, lane = tid & 63, wid = tid >> 6;
    const int wm = (wid >> 2) * 128, wnb = wid & 3, l15 = lane & 15, lk = lane >> 4;
    const int hc = hc0 + wnb * 16 + l15;
#pragma unroll
    for (int mf = 0; mf < 8; ++mf)
#pragma unroll
        for (int r = 0; r < 4; ++r) {
            const int row = m0 + wm + mf * 16 + lk * 4 + r;
            float p[4];
#pragma unroll
            for (int g = 0; g < 4; ++g) {
                const int R = g * 1024 + hc;
                p[g] = acc[mf][g][r] + Z1[(size_t)row * 4096 + R];
                if (step == 0) p[g] += flagcol[R];
            }
            const float ig = sigmoidf_(p[0]);
            const float fg = sigmoidf_(p[1]);
            const float gg = tanhf(p[2]);
            const float og = sigmoidf_(p[3]);
            const int idx = row * 1024 + hc;
            const float cold = (step == 0) ? 0.0f : c1[idx];
            const float cn = fg * cold + ig * gg;
            c1[idx] = cn;
            const float h = og * tanhf(cn);
            const f16 hh = (f16)h;
            const f16 hl = (f16)(h - (float)hh);
            h1hi_out[idx] = hh; h1lo_out[idx] = hl;
            const bool pos = h > 0.0f;
            acthi[idx] = pos ? hh : (f16)0.0f;
            actlo[idx] = pos ? hl : (f16)0.0f;
        }
}

// Layer-2 cell: gates = b2 + act@Wih2^T + h2@Whh2^T
__global__ __launch_bounds__(512) void k_stepB(
    const f16* __restrict__ acthi, const f16* __restrict__ actlo,
    const float* __restrict__ Wih2,
    const f16* __restrict__ h2hi_in, const f16* __restrict__ h2lo_in,
    const float* __restrict__ Whh2,
    const float* __restrict__ bih2, const float* __restrict__ bhh2,
    float* __restrict__ c2, f16* __restrict__ h2hi_out, f16* __restrict__ h2lo_out,
    const unsigned* __restrict__ cnt_prev, int step)
{
    if (step > 0 && cnt_prev[0] == 0u) return;
    __shared__ __align__(16) char sm[2 * BUFSZ];
    int m0, hc0; block_tile(m0, hc0);
    f32x4 acc[8][4];
#pragma unroll
    for (int a = 0; a < 8; ++a)
#pragma unroll
        for (int b = 0; b < 4; ++b) acc[a][b] = (f32x4){0.f, 0.f, 0.f, 0.f};
    pass256<false>(acthi, actlo, nullptr, nullptr, Wih2, m0, hc0, acc, sm);
    if (step > 0)
        pass256<false>(h2hi_in, h2lo_in, nullptr, nullptr, Whh2, m0, hc0, acc, sm);

    const int tid = threadIdx.x, lane = tid & 63, wid = tid >> 6;
    const int wm = (wid >> 2) * 128, wnb = wid & 3, l15 = lane & 15, lk = lane >> 4;
    const int hc = hc0 + wnb * 16 + l15;
#pragma unroll
    for (int mf = 0; mf < 8; ++mf)
#pragma unroll
        for (int r = 0; r < 4; ++r) {
            const int row = m0 + wm + mf * 16 + lk * 4 + r;
            float p[4];
#pragma unroll
            for (int g = 0; g < 4; ++g) {
                const int R = g * 1024 + hc;
                p[g] = acc[mf][g][r] + bih2[R] + bhh2[R];
            }
            const float ig = sigmoidf_(p[0]);
            const float fg = sigmoidf_(p[1]);
            const float gg = tanhf(p[2]);
            const float og = sigmoidf_(p[3]);
            const int idx = row * 1024 + hc;
            const float cold = (step == 0) ? 0.0f : c2[idx];
            const float cn = fg * cold + ig * gg;
            c2[idx] = cn;
            const float h = og * tanhf(cn);
            const f16 hh = (f16)h;
            h2hi_out[idx] = hh;
            h2lo_out[idx] = (f16)(h - (float)hh);
        }
}

// Merged halting state machine + acc_out accumulate (one wave per row).
__global__ __launch_bounds__(256) void k_haltacc(
    const f16* __restrict__ h2hi, const f16* __restrict__ h2lo,
    const float* __restrict__ Whalt, const float* __restrict__ bhalt,
    float* __restrict__ halt, float* __restrict__ cont,
    float* __restrict__ ponder_out, unsigned* __restrict__ ctrl,
    float* __restrict__ acc_out,
    const unsigned* __restrict__ cnt_prev, int step)
{
    if (step > 0 && cnt_prev[0] == 0u) return;
    const int lane = threadIdx.x & 63;
    const int b = blockIdx.x * 4 + (threadIdx.x >> 6);
    const size_t base = (size_t)b * 1024;
    float sum = 0.0f;
    for (int k = lane; k < 1024; k += 64)
        sum += ((float)h2hi[base + k] + (float)h2lo[base + k]) * Whalt[k];
#pragma unroll
    for (int off = 32; off > 0; off >>= 1) sum += __shfl_down(sum, off, 64);
    float co = 0.0f;
    if (lane == 0) {
        const float sh = sigmoidf_(sum + bhalt[0]);
        if (cont[b] != 0.0f) {
            const float hn = halt[b] + sh;
            const bool ending = hn > 0.99f;
            co = sh + (ending ? (1.0f - hn) : 0.0f);
            halt[b] = hn;
            if (!ending) {
                ponder_out[b] += 1.0f;
                atomicAdd(&ctrl[step], 1u);
            } else {
                cont[b] = 0.0f;
            }
        }
        if (b == 0) ctrl[12] = (unsigned)(step + 1);
    }
    co = __shfl(co, 0, 64);
    if (step == 0 || co != 0.0f) {
        float4* dst = (float4*)(acc_out + base);
        const f16x4* hi4 = (const f16x4*)(h2hi + base);
        const f16x4* lo4 = (const f16x4*)(h2lo + base);
#pragma unroll
        for (int j = 0; j < 4; ++j) {
            const int i = lane + 64 * j;
            const f16x4 hv = hi4[i];
            const f16x4 lv = lo4[i];
            float4 d = (step == 0) ? (float4){0.f, 0.f, 0.f, 0.f} : dst[i];
            d.x = fmaf(co, (float)hv[0] + (float)lv[0], d.x);
            d.y = fmaf(co, (float)hv[1] + (float)lv[1], d.y);
            d.z = fmaf(co, (float)hv[2] + (float)lv[2], d.z);
            d.w = fmaf(co, (float)hv[3] + (float)lv[3], d.w);
            dst[i] = d;
        }
    }
}

__global__ __launch_bounds__(256) void k_small_init(
    float* __restrict__ halt, float* __restrict__ cont,
    float* __restrict__ ponder_out, unsigned* __restrict__ ctrl)
{
    const int b = blockIdx.x * 256 + threadIdx.x;
    if (b < 4096) { halt[b] = 0.0f; cont[b] = 1.0f; ponder_out[b] = 0.0f; }
    if (b < 16) ctrl[b] = 0u;
}

// flat fp32 -> f16 hi/lo pairs (4096*1024 elements)
__global__ __launch_bounds__(256) void k_split_flat(
    const float* __restrict__ src, f16* __restrict__ hi, f16* __restrict__ lo)
{
    const size_t i = ((size_t)blockIdx.x * 256 + threadIdx.x) * 4;
    const float4 v = *(const float4*)(src + i);
    const f16 s0 = (f16)v.x, s1 = (f16)v.y, s2 = (f16)v.z, s3 = (f16)v.w;
    const f16x4 hv = {s0, s1, s2, s3};
    const f16x4 lw = {(f16)(v.x - (float)s0), (f16)(v.y - (float)s1),
                      (f16)(v.z - (float)s2), (f16)(v.w - (float)s3)};
    *(f16x4*)(hi + i) = hv;
    *(f16x4*)(lo + i) = lw;
}

// Wih1 [4096][1025]: cols 0..1023 -> pairs; col 1024 -> flagcol
__global__ __launch_bounds__(256) void k_split_wih1(
    const float* __restrict__ src, f16* __restrict__ hi, f16* __restrict__ lo,
    float* __restrict__ flagcol)
{
    const int t = blockIdx.x * 256 + threadIdx.x;
    const int row = t >> 8, c4 = (t & 255) << 2;
    const float* s = src + (size_t)row * 1025 + c4;
    const float v0 = s[0], v1 = s[1], v2 = s[2], v3 = s[3];
    const f16 s0 = (f16)v0, s1 = (f16)v1, s2 = (f16)v2, s3 = (f16)v3;
    const f16x4 hv = {s0, s1, s2, s3};
    const f16x4 lw = {(f16)(v0 - (float)s0), (f16)(v1 - (float)s1),
                      (f16)(v2 - (float)s2), (f16)(v3 - (float)s3)};
    const size_t di = (size_t)row * 1024 + c4;
    *(f16x4*)(hi + di) = hv;
    *(f16x4*)(lo + di) = lw;
    if ((t & 255) == 0) flagcol[row] = src[(size_t)row * 1025 + 1024];
}

__global__ __launch_bounds__(256) void k_fin1(
    const f16* __restrict__ h1hi0, const f16* __restrict__ h1hi1,
    const f16* __restrict__ h1lo0, const f16* __restrict__ h1lo1,
    const f16* __restrict__ h2hi0, const f16* __restrict__ h2hi1,
    const f16* __restrict__ h2lo0, const f16* __restrict__ h2lo1,
    const float* __restrict__ c1s, const float* __restrict__ c2s,
    const float* __restrict__ halt, const float* __restrict__ cont,
    const unsigned* __restrict__ ctrl, float* __restrict__ out)
{
    const int par = (int)(ctrl[12] & 1u);
    const f16* h1h = par ? h1hi1 : h1hi0;
    const f16* h1l = par ? h1lo1 : h1lo0;
    const f16* h2h = par ? h2hi1 : h2hi0;
    const f16* h2l = par ? h2lo1 : h2lo0;
    const int b = blockIdx.x;
    const float rem = (cont[b] != 0.0f) ? (1.0f - halt[b]) : 0.0f;
    const int base = b * 1024;
    for (int i = threadIdx.x; i < 1024; i += 256) {
        const float h1v = (float)h1h[base + i] + (float)h1l[base + i];
        const float h2v = (float)h2h[base + i] + (float)h2l[base + i];
        out[O_H1 + base + i] = h1v;
        out[O_C1 + base + i] = c1s[base + i];
        out[O_H2 + base + i] = h2v;
        out[O_C2 + base + i] = c2s[base + i];
        if (rem != 0.0f) out[O_ACC + base + i] += rem * h2v;
    }
}

__global__ __launch_bounds__(256) void k_fin2(
    const float* __restrict__ halt, float* __restrict__ out)
{
    __shared__ float red[256];
    float s = 0.0f;
    for (int i = threadIdx.x; i < 4096; i += 256) s += halt[i];
    red[threadIdx.x] = s;
    __syncthreads();
    for (int w = 128; w > 0; w >>= 1) {
        if (threadIdx.x < w) red[threadIdx.x] += red[threadIdx.x + w];
        __syncthreads();
    }
    if (threadIdx.x == 0) out[O_PCOST] = -0.01f * (red[0] * (1.0f / 4096.0f));
}

extern "C" void kernel_launch(void* const* d_in, const int* in_sizes, int n_in,
                              void* d_out, int out_size, void* d_ws, size_t ws_size,
                              hipStream_t stream) {
    const float* inputs = (const float*)d_in[0];
    const float* W_ih1  = (const float*)d_in[1];
    const float* W_hh1  = (const float*)d_in[2];
    const float* b_ih1  = (const float*)d_in[3];
    const float* b_hh1  = (const float*)d_in[4];
    const float* W_ih2  = (const float*)d_in[5];
    const float* W_hh2  = (const float*)d_in[6];
    const float* b_ih2  = (const float*)d_in[7];
    const float* b_hh2  = (const float*)d_in[8];
    const float* W_halt = (const float*)d_in[9];
    const float* b_halt = (const float*)d_in[10];

    float* out = (float*)d_out;
    float* Z1  = out + O_H1;                  // 64 MB in d_out's dead state region

    char* wsb = (char*)d_ws;
    float* c1s = (float*)(wsb + WS_C1);
    float* c2s = (float*)(wsb + WS_C2);
    f16* h1hi[2] = { (f16*)(wsb + WS_H1HI0), (f16*)(wsb + WS_H1HI1) };
    f16* h1lo[2] = { (f16*)(wsb + WS_H1LO0), (f16*)(wsb + WS_H1LO1) };
    f16* h2hi[2] = { (f16*)(wsb + WS_H2HI0), (f16*)(wsb + WS_H2HI1) };
    f16* h2lo[2] = { (f16*)(wsb + WS_H2LO0), (f16*)(wsb + WS_H2LO1) };
    f16* acthi   = (f16*)(wsb + WS_ACTHI);
    f16* actlo   = (f16*)(wsb + WS_ACTLO);
    float* halt    = (float*)(wsb + WS_MISC);
    float* cont    = halt + 4096;
    float* coef    = cont + 4096;
    float* flagcol = coef + 4096;
    unsigned* ctrl = (unsigned*)(flagcol + 4096);

    // x / W1 pairs live in the step-0-dead h ping-pong set 0 slots
    f16* xhi  = h1hi[0]; f16* xlo  = h1lo[0];
    f16* W1hi = h2hi[0]; f16* W1lo = h2lo[0];

    k_small_init<<<16, 256, 0, stream>>>(halt, cont, out + O_PSTEP, ctrl);

    k_split_wih1<<<4096, 256, 0, stream>>>(W_ih1, W1hi, W1lo, flagcol);
    k_split_flat<<<4096, 256, 0, stream>>>(inputs, xhi, xlo);
    k_z1<<<256, 512, 0, stream>>>(xhi, xlo, W1hi, W1lo, b_ih1, b_hh1, Z1);

    for (int s = 0; s < TSTEPS; ++s) {
        const int wsel = (s & 1) ? 0 : 1;
        const int rsel = 1 - wsel;
        const unsigned* cnt_prev = ctrl + (s > 0 ? s - 1 : 0);

        k_stepA<<<256, 512, 0, stream>>>(Z1, W_hh1, h1hi[rsel], h1lo[rsel],
                                         flagcol, c1s,
                                         h1hi[wsel], h1lo[wsel], acthi, actlo,
                                         cnt_prev, s);
        k_stepB<<<256, 512, 0, stream>>>(acthi, actlo, W_ih2,
                                         h2hi[rsel], h2lo[rsel], W_hh2,
                                         b_ih2, b_hh2, c2s,
                                         h2hi[wsel], h2lo[wsel],
                                         cnt_prev, s);
        k_haltacc<<<1024, 256, 0, stream>>>(h2hi[wsel], h2lo[wsel], W_halt, b_halt,
                                            halt, cont, out + O_PSTEP, ctrl,
                                            out + O_ACC, cnt_prev, s);
    }

    k_fin1<<<4096, 256, 0, stream>>>(h1hi[0], h1hi[1], h1lo[0], h1lo[1],
                                     h2hi[0], h2hi[1], h2lo[0], h2lo[1],
                                     c1s, c2s, halt, cont, ctrl, out);
    k_fin2<<<1, 256, 0, stream>>>(halt, out);
}